// Round 9
// baseline (471.677 us; speedup 1.0000x reference)
//
#include <hip/hip_runtime.h>

#define EPS 1e-5f
#define VSCALE 20.0f

typedef __attribute__((ext_vector_type(8))) short sh8;
typedef __attribute__((ext_vector_type(4))) float f4;
typedef __attribute__((ext_vector_type(2))) _Float16 h2f;

static __device__ __forceinline__ unsigned short f2b(float f) {
    union { float f; unsigned u; } v; v.f = f;
    unsigned r = v.u + 0x7FFF + ((v.u >> 16) & 1);  // RNE
    return (unsigned short)(r >> 16);
}
static __device__ __forceinline__ float b2f(unsigned short b) {
    union { unsigned u; float f; } v; v.u = ((unsigned)b) << 16; return v.f;
}
static __device__ __forceinline__ unsigned pk2(float a, float b) {
    return (unsigned)f2b(a) | ((unsigned)f2b(b) << 16);
}
static __device__ __forceinline__ h2f u2h(unsigned u) {
    union { unsigned u; h2f h; } c; c.u = u; return c.h;
}
static __device__ __forceinline__ float dot2h(h2f a, h2f b, float c) {
#if __has_builtin(__builtin_amdgcn_fdot2)
    return __builtin_amdgcn_fdot2(a, b, c, false);
#else
    return (float)a.x * (float)b.x + (float)a.y * (float)b.y + c;
#endif
}
// u8 lane extracts as float (v_cvt_f32_ubyteN when available)
#if __has_builtin(__builtin_amdgcn_cvt_f32_ubyte0)
#define UB0(x) __builtin_amdgcn_cvt_f32_ubyte0(x)
#define UB1(x) __builtin_amdgcn_cvt_f32_ubyte1(x)
#define UB2(x) __builtin_amdgcn_cvt_f32_ubyte2(x)
#define UB3(x) __builtin_amdgcn_cvt_f32_ubyte3(x)
#else
#define UB0(x) ((float)((x) & 0xffu))
#define UB1(x) ((float)(((x) >> 8) & 0xffu))
#define UB2(x) ((float)(((x) >> 16) & 0xffu))
#define UB3(x) ((float)((x) >> 24))
#endif

// raw barrier: lgkmcnt-only (never drains vmcnt -> prefetch stays in flight)
static __device__ __forceinline__ void barrier_raw() {
    __builtin_amdgcn_sched_barrier(0);
    asm volatile("s_waitcnt lgkmcnt(0)" ::: "memory");
    __builtin_amdgcn_s_barrier();
    __builtin_amdgcn_sched_barrier(0);
}

// ===================== weight prep (all 6, one launch) =====================
__global__ __launch_bounds__(256) void prep_all_k(
    const float* __restrict__ Wq, const float* __restrict__ Wk,
    const float* __restrict__ Wv, const float* __restrict__ Wo,
    const float* __restrict__ Wf1, const float* __restrict__ Wf2,
    unsigned short* __restrict__ Wt)
{
    int i = blockIdx.x * 256 + threadIdx.x;      // 0..131071
    if (i < 65536) {
        int s = i >> 14;
        const float* W = (s == 0) ? Wq : (s == 1) ? Wk : (s == 2) ? Wv : Wo;
        int l = i & 16383, k = l >> 7, n = l & 127;
        Wt[(i & ~16383) + n * 128 + k] = f2b(W[l]);
    } else if (i < 98304) {
        int l = i - 65536, k = l >> 8, n = l & 255;
        Wt[65536 + n * 128 + k] = f2b(Wf1[l]);
    } else {
        int l = i - 98304, k = l >> 7, n = l & 127;
        Wt[98304 + n * 256 + k] = f2b(Wf2[l]);
    }
}

// ===================== QKV: persistent streaming GEMM, W in registers ======
// (512,4): VGPR cap 128 (est ~100, no spill), 2 blocks/CU via 32KB LDS.
__global__ __launch_bounds__(512, 4) void qkv3_k(
    const float* __restrict__ h, const unsigned short* __restrict__ Wt,
    _Float16* __restrict__ Qh, unsigned char* __restrict__ KV,
    int M, int tiles)
{
    constexpr int KD = 128, PER = 2;
    __shared__ __align__(16) unsigned short As[2][64 * KD];
    const int tid = threadIdx.x;
    const int wave = tid >> 6, lane = tid & 63;
    const int q = lane >> 4, lm = lane & 15;
    const int wr = wave >> 2, wc = wave & 3;     // 2 row-halves x 4 col-quarters
    const int wv = blockIdx.y;                   // 0=Q 1=K 2=V
    const unsigned short* Wblk = Wt + (size_t)wv * 16384;

    // ---- prologue A prefetch (fp32, 2 float4 per chunk) ----
    float4 rAf[PER][2];
    {
        const int rowT = blockIdx.x * 64;
#pragma unroll
        for (int i = 0; i < PER; ++i) {
            int g = tid + i * 512;
            int row = g >> 4, ch = g & 15;
            int grow = rowT + row; if (grow >= M) grow = M - 1;
            const float* p = &h[(size_t)grow * 128 + ch * 8];
            rAf[i][0] = *(const float4*)p;
            rAf[i][1] = *(const float4*)(p + 4);
        }
    }

    // ---- W fragments -> registers (once) ----
    sh8 wfr[2][4];
#pragma unroll
    for (int ni = 0; ni < 2; ++ni)
#pragma unroll
        for (int kc = 0; kc < 4; ++kc)
            wfr[ni][kc] = *(const sh8*)&Wblk[(size_t)(wc * 32 + ni * 16 + lm) * KD
                                             + (kc * 4 + q) * 8];

    int cur = 0;
    for (int t = blockIdx.x; t < tiles; t += gridDim.x) {
        const int rowT = t * 64;
        barrier_raw();                        // As[cur] free
        unsigned short* Asc = As[cur];
#pragma unroll
        for (int i = 0; i < PER; ++i) {       // convert + write (waits via dep)
            int g = tid + i * 512;
            int row = g >> 4, ch = g & 15;
            uint4 v;
            v.x = pk2(rAf[i][0].x, rAf[i][0].y);
            v.y = pk2(rAf[i][0].z, rAf[i][0].w);
            v.z = pk2(rAf[i][1].x, rAf[i][1].y);
            v.w = pk2(rAf[i][1].z, rAf[i][1].w);
            *(uint4*)&Asc[row * KD + ((ch ^ (row & 7)) * 8)] = v;
        }
        const int tn = t + (int)gridDim.x;
        if (tn < tiles) {                     // issue next prefetch NOW
            const int rowTn = tn * 64;
#pragma unroll
            for (int i = 0; i < PER; ++i) {
                int g = tid + i * 512;
                int row = g >> 4, ch = g & 15;
                int grow = rowTn + row; if (grow >= M) grow = M - 1;
                const float* p = &h[(size_t)grow * 128 + ch * 8];
                rAf[i][0] = *(const float4*)p;
                rAf[i][1] = *(const float4*)(p + 4);
            }
        }
        barrier_raw();                        // As[cur] visible

        f4 acc[2][2];
#pragma unroll
        for (int mi = 0; mi < 2; ++mi)
#pragma unroll
            for (int ni = 0; ni < 2; ++ni) {
                f4 z = {0.f, 0.f, 0.f, 0.f};
                acc[mi][ni] = z;
            }
#pragma unroll
        for (int kc = 0; kc < 4; ++kc) {
            sh8 af[2];
#pragma unroll
            for (int mi = 0; mi < 2; ++mi) {
                const int row = wr * 32 + mi * 16 + lm;
                af[mi] = *(const sh8*)&Asc[row * KD + (((kc * 4 + q) ^ (row & 7)) * 8)];
            }
#pragma unroll
            for (int mi = 0; mi < 2; ++mi)
#pragma unroll
                for (int ni = 0; ni < 2; ++ni)
                    acc[mi][ni] = __builtin_amdgcn_mfma_f32_16x16x32_bf16(
                        af[mi], wfr[ni][kc], acc[mi][ni], 0, 0, 0);
        }

        // ---- epilogue ----
#pragma unroll
        for (int ni = 0; ni < 2; ++ni) {
            const int col = wc * 32 + ni * 16 + lm;
#pragma unroll
            for (int mi = 0; mi < 2; ++mi) {
#pragma unroll
                for (int r = 0; r < 4; ++r) {
                    const int row = rowT + wr * 32 + mi * 16 + q * 4 + r;
                    if (row >= M) continue;
                    const float v = acc[mi][ni][r];
                    if (wv == 0) Qh[(size_t)row * 128 + col] = (_Float16)v;
                    else if (wv == 1)
                        *(_Float16*)(KV + (size_t)row * 384 + col * 2) = (_Float16)v;
                    else {
                        float tt = rintf(v * VSCALE);
                        tt = fminf(fmaxf(tt, -127.f), 127.f);
                        KV[(size_t)row * 384 + 256 + col] = (unsigned char)(int)(tt + 128.f);
                    }
                }
            }
        }
        cur ^= 1;
    }
}

// ========== persistent streaming GEMM, W in registers ======================
// Geometry per KD keeps VGPR <= 128 (no spill at (512,4)):
//  KD=128: 64-row tiles, waves 2x4 (32 cols each), wfr[2][4]=32 VGPR.
//  KD=256: 32-row tiles, waves 1x8 (16 cols each), wfr[1][8]=32 VGPR.
// As = 32KB both -> 2 blocks/CU. Same per-output MFMA chain order ->
// bit-identical numerics vs gemm2_k.
template<int KD, int RES, int STATS, int RELU>
__global__ __launch_bounds__(512, 4) void gemm3_k(
    const unsigned short* __restrict__ A, const unsigned short* __restrict__ Wt,
    const float* __restrict__ bias, const void* __restrict__ resid,
    unsigned short* __restrict__ C, int M, int ldc, int tiles,
    const float* __restrict__ aff1, float* __restrict__ ostats)
{
    constexpr int CPR = KD / 8;               // 16B chunks per row
    constexpr int NWC = (KD == 128) ? 4 : 8;  // wave-columns
    constexpr int NI  = (KD == 128) ? 2 : 1;  // 16-col fragments per wave
    constexpr int TM  = (KD == 128) ? 64 : 32;// rows per tile
    constexpr int PER = TM * CPR / 512;       // staged chunks per thread
    constexpr int KC  = KD / 32;              // mfma K-steps
    __shared__ __align__(16) unsigned short As[2][TM * KD];
    __shared__ float sacc[256];
    const int tid = threadIdx.x;
    const int wave = tid >> 6, lane = tid & 63;
    const int q = lane >> 4, lm = lane & 15;
    const int wr = wave / NWC, wc = wave % NWC;
    const int colBase = blockIdx.y * 128;
    const unsigned short* Wblk = Wt + (size_t)colBase * KD;

    // ---- prologue A prefetch (issue first) ----
    uint4 rA[PER];
    {
        const int rowT = blockIdx.x * TM;
#pragma unroll
        for (int i = 0; i < PER; ++i) {
            int g = tid + i * 512;
            int row = g / CPR, ch = g % CPR;
            int grow = rowT + row; if (grow >= M) grow = M - 1;
            rA[i] = *(const uint4*)&A[(size_t)grow * KD + ch * 8];
        }
    }

    // ---- W fragments -> registers (once) ----
    sh8 wfr[NI][KC];
#pragma unroll
    for (int ni = 0; ni < NI; ++ni)
#pragma unroll
        for (int kc = 0; kc < KC; ++kc)
            wfr[ni][kc] = *(const sh8*)&Wblk[(size_t)(wc * (16 * NI) + ni * 16 + lm) * KD
                                             + (kc * 4 + q) * 8];
    if (STATS && tid < 256) sacc[tid] = 0.f;

    // ---- per-lane epilogue constants ----
    float bv[NI], rsc[NI], rsh[NI];
#pragma unroll
    for (int ni = 0; ni < NI; ++ni) {
        const int col = colBase + wc * (16 * NI) + ni * 16 + lm;
        bv[ni] = bias[col];
        if (RES == 3) { rsc[ni] = aff1[col]; rsh[ni] = aff1[128 + col]; }
        else { rsc[ni] = 0.f; rsh[ni] = 0.f; }
    }
    float st_s[NI], st_ss[NI];
#pragma unroll
    for (int ni = 0; ni < NI; ++ni) { st_s[ni] = 0.f; st_ss[ni] = 0.f; }

    int cur = 0;
    for (int t = blockIdx.x; t < tiles; t += gridDim.x) {
        const int rowT = t * TM;
        barrier_raw();                        // As[cur] free
        unsigned short* Asc = As[cur];
#pragma unroll
        for (int i = 0; i < PER; ++i) {       // waits vmcnt via rA register dep
            int g = tid + i * 512;
            int row = g / CPR, ch = g % CPR;
            *(uint4*)&Asc[row * KD + ((ch ^ (row & 7)) * 8)] = rA[i];
        }
        const int tn = t + (int)gridDim.x;
        if (tn < tiles) {                     // issue next prefetch NOW
            const int rowTn = tn * TM;
#pragma unroll
            for (int i = 0; i < PER; ++i) {
                int g = tid + i * 512;
                int row = g / CPR, ch = g % CPR;
                int grow = rowTn + row; if (grow >= M) grow = M - 1;
                rA[i] = *(const uint4*)&A[(size_t)grow * KD + ch * 8];
            }
        }
        barrier_raw();                        // As[cur] visible

        f4 acc[2][NI];
#pragma unroll
        for (int mi = 0; mi < 2; ++mi)
#pragma unroll
            for (int ni = 0; ni < NI; ++ni) {
                f4 z = {0.f, 0.f, 0.f, 0.f};
                acc[mi][ni] = z;
            }
#pragma unroll
        for (int kc = 0; kc < KC; ++kc) {
            sh8 af[2];
#pragma unroll
            for (int mi = 0; mi < 2; ++mi) {
                const int row = wr * 32 + mi * 16 + lm;
                af[mi] = *(const sh8*)&Asc[row * KD + (((kc * 4 + q) ^ (row & 7)) * 8)];
            }
#pragma unroll
            for (int mi = 0; mi < 2; ++mi)
#pragma unroll
                for (int ni = 0; ni < NI; ++ni)
                    acc[mi][ni] = __builtin_amdgcn_mfma_f32_16x16x32_bf16(
                        af[mi], wfr[ni][kc], acc[mi][ni], 0, 0, 0);
        }

        // ---- epilogue (per-lane, round-0 numerics) ----
#pragma unroll
        for (int ni = 0; ni < NI; ++ni) {
            const int col = colBase + wc * (16 * NI) + ni * 16 + lm;
#pragma unroll
            for (int mi = 0; mi < 2; ++mi) {
#pragma unroll
                for (int r = 0; r < 4; ++r) {
                    const int row = rowT + wr * 32 + mi * 16 + q * 4 + r;
                    if (row >= M) continue;
                    float val = acc[mi][ni][r] + bv[ni];
                    if (RES == 1)
                        val += ((const float*)resid)[(size_t)row * ldc + col];
                    if (RES == 3)
                        val += b2f(((const unsigned short*)resid)[(size_t)row * ldc + col])
                               * rsc[ni] + rsh[ni];
                    if (RELU) val = fmaxf(val, 0.f);
                    if (STATS) { st_s[ni] += val; st_ss[ni] += val * val; }
                    C[(size_t)row * ldc + col] = f2b(val);
                }
            }
        }
        cur ^= 1;
    }

    // ---- stats tail ----
    if (STATS) {
        barrier_raw();
#pragma unroll
        for (int ni = 0; ni < NI; ++ni) {
            st_s[ni]  += __shfl_xor(st_s[ni], 16);  st_s[ni]  += __shfl_xor(st_s[ni], 32);
            st_ss[ni] += __shfl_xor(st_ss[ni], 16); st_ss[ni] += __shfl_xor(st_ss[ni], 32);
            if (q == 0) {
                const int c = wc * (16 * NI) + ni * 16 + lm;
                atomicAdd(&sacc[c], st_s[ni]);
                atomicAdd(&sacc[128 + c], st_ss[ni]);
            }
        }
        barrier_raw();
        if (tid < 128) {
            atomicAdd(&ostats[tid], sacc[tid]);
            atomicAdd(&ostats[128 + tid], sacc[128 + tid]);
        }
    }
}

// ============== BN1 fold into FFN1 weights =================================
__global__ __launch_bounds__(256) void fold_bn1_k(
    const unsigned short* __restrict__ W1t, const float* __restrict__ rstats,
    const float* __restrict__ g1, const float* __restrict__ b1,
    const float* __restrict__ bf1, float invN,
    unsigned short* __restrict__ W1f, float* __restrict__ b1f,
    float* __restrict__ aff1)
{
    __shared__ float sc[128], sh[128];
    const int t = threadIdx.x;
    if (t < 128) {
        const float mu = rstats[t] * invN;
        const float var = rstats[128 + t] * invN - mu * mu;
        const float isg = rsqrtf(var + EPS) * g1[t];
        const float shf = b1[t] - mu * isg;
        sc[t] = isg; sh[t] = shf;
        aff1[t] = isg; aff1[128 + t] = shf;
    }
    __syncthreads();
    float acc = bf1[t];
#pragma unroll
    for (int c = 0; c < 128; c += 8) {
        const uint4 v = *(const uint4*)&W1t[t * 128 + c];
        const float w0 = b2f((unsigned short)(v.x & 0xffff));
        const float w1 = b2f((unsigned short)(v.x >> 16));
        const float w2 = b2f((unsigned short)(v.y & 0xffff));
        const float w3 = b2f((unsigned short)(v.y >> 16));
        const float w4 = b2f((unsigned short)(v.z & 0xffff));
        const float w5 = b2f((unsigned short)(v.z >> 16));
        const float w6 = b2f((unsigned short)(v.w & 0xffff));
        const float w7 = b2f((unsigned short)(v.w >> 16));
        acc += sh[c] * w0 + sh[c + 1] * w1 + sh[c + 2] * w2 + sh[c + 3] * w3
             + sh[c + 4] * w4 + sh[c + 5] * w5 + sh[c + 6] * w6 + sh[c + 7] * w7;
        uint4 o;
        o.x = pk2(w0 * sc[c],     w1 * sc[c + 1]);
        o.y = pk2(w2 * sc[c + 2], w3 * sc[c + 3]);
        o.z = pk2(w4 * sc[c + 4], w5 * sc[c + 5]);
        o.w = pk2(w6 * sc[c + 6], w7 * sc[c + 7]);
        *(uint4*)&W1f[t * 128 + c] = o;
    }
    b1f[t] = acc;
}

// ============== CSR build: two-level LDS counting sort =====================
__global__ __launch_bounds__(256) void bucket_cnt_k(const int* __restrict__ dst,
                                                    int E, int* __restrict__ bCnt)
{
    __shared__ int c[512];
    const int t = threadIdx.x;
    c[t] = 0; c[t + 256] = 0;
    __syncthreads();
    for (int i = blockIdx.x * 256 + t; i < E; i += gridDim.x * 256)
        atomicAdd(&c[dst[i] >> 8], 1);
    __syncthreads();
    if (c[t]) atomicAdd(&bCnt[t], c[t]);
    if (c[t + 256]) atomicAdd(&bCnt[t + 256], c[t + 256]);
}

__global__ __launch_bounds__(512) void bucket_scan_k(const int* __restrict__ bCnt,
                                                     int B, int* __restrict__ bOff,
                                                     int* __restrict__ bCur)
{
    __shared__ int ts[512];
    const int t = threadIdx.x;
    const int v = (t < B) ? bCnt[t] : 0;
    ts[t] = v;
    __syncthreads();
    for (int o = 1; o < 512; o <<= 1) {
        int u = (t >= o) ? ts[t - o] : 0;
        __syncthreads();
        ts[t] += u;
        __syncthreads();
    }
    const int ex = ts[t] - v;
    if (t < B) { bOff[t] = ex; bCur[t] = ex; }
    if (t == B - 1) bOff[B] = ex + v;
}

#define CCH 8192
__global__ __launch_bounds__(512) void coarse_k(const int* __restrict__ src,
                                                const int* __restrict__ dst, int E,
                                                int* __restrict__ bCur,
                                                unsigned* __restrict__ coarse)
{
    __shared__ int cnt[512], off[512], gbase[512], rc[512];
    __shared__ unsigned pk[CCH];
    __shared__ int ga[CCH];
    const int t = threadIdx.x;
    const int e0 = blockIdx.x * CCH;
    const int n = min(CCH, E - e0);
    cnt[t] = 0;
    __syncthreads();
    for (int i = t; i < n; i += 512) atomicAdd(&cnt[dst[e0 + i] >> 8], 1);
    __syncthreads();
    const int v = cnt[t];
    off[t] = v;
    __syncthreads();
    for (int o = 1; o < 512; o <<= 1) {
        int u = (t >= o) ? off[t - o] : 0;
        __syncthreads();
        off[t] += u;
        __syncthreads();
    }
    const int ex = off[t] - v;
    off[t] = ex;
    if (v > 0) gbase[t] = atomicAdd(&bCur[t], v);
    rc[t] = 0;
    __syncthreads();
    for (int i = t; i < n; i += 512) {
        const int d = dst[e0 + i], s = src[e0 + i];
        const int b = d >> 8;
        const int j = atomicAdd(&rc[b], 1);
        const int slot = off[b] + j;
        pk[slot] = ((unsigned)(d & 255) << 17) | (unsigned)s;
        ga[slot] = gbase[b] + j;
    }
    __syncthreads();
    for (int i = t; i < n; i += 512) coarse[ga[i]] = pk[i];
}

__global__ __launch_bounds__(256) void fine_k(const unsigned* __restrict__ coarse,
                                              const int* __restrict__ bOff, int B,
                                              int Nn, int* __restrict__ row_ptr,
                                              int* __restrict__ esrc)
{
    __shared__ int cnt[256], off[256], rc[256];
    const int t = threadIdx.x;
    const int b = blockIdx.x;
    const int base = b << 8;
    const int e0 = bOff[b], e1 = bOff[b + 1];
    cnt[t] = 0;
    __syncthreads();
    for (int i = e0 + t; i < e1; i += 256)
        atomicAdd(&cnt[(coarse[i] >> 17) & 255], 1);
    __syncthreads();
    const int v = cnt[t];
    off[t] = v;
    __syncthreads();
    for (int o = 1; o < 256; o <<= 1) {
        int u = (t >= o) ? off[t - o] : 0;
        __syncthreads();
        off[t] += u;
        __syncthreads();
    }
    const int ex = off[t] - v;
    off[t] = ex;
    rc[t] = 0;
    if (base + t < Nn) row_ptr[base + t] = e0 + ex;
    if (b == B - 1 && t == 0) row_ptr[Nn] = e1;
    __syncthreads();
    for (int i = e0 + t; i < e1; i += 256) {
        const unsigned p = coarse[i];
        const int l = (p >> 17) & 255;
        const int j = atomicAdd(&rc[l], 1);
        esrc[e0 + off[l] + j] = (int)(p & 0x1FFFFu);
    }
}

// ============================ edge attention ===============================
// Node-range split across 3 dispatches purely for profiling granularity:
// blocks independent per node, outputs bit-identical (verified round 6).
#define EA_ACC(kc, vc, EI) do {                                              \
    float sp = dot2h(u2h((kc).w), q3, dot2h(u2h((kc).z), q2,                 \
               dot2h(u2h((kc).y), q1, dot2h(u2h((kc).x), q0, 0.f))));        \
    sp += __shfl_xor(sp, 1);                                                 \
    float sc = __expf(fminf(fmaxf(sp * 0.25f, -5.f), 5.f));                  \
    sc = ((EI) < nb) ? sc : 0.f;                                             \
    a0 += sc * UB0((vc).x);                                                  \
    a1 += sc * UB1((vc).x);                                                  \
    a2 += sc * UB2((vc).x);                                                  \
    a3 += sc * UB3((vc).x);                                                  \
    a4 += sc * UB0((vc).y);                                                  \
    a5 += sc * UB1((vc).y);                                                  \
    a6 += sc * UB2((vc).y);                                                  \
    a7 += sc * UB3((vc).y);                                                  \
    z += sc;                                                                 \
} while (0)

__global__ __launch_bounds__(256) void edge_attn_k(
    const _Float16* __restrict__ Qh, const unsigned char* __restrict__ KV,
    const int* __restrict__ row_ptr, const int* __restrict__ esrc,
    unsigned short* __restrict__ attnb, int nodeOff, int nodeEnd)
{
    const int wave = threadIdx.x >> 6, lane = threadIdx.x & 63;
    const int node = nodeOff + blockIdx.x * 4 + wave;
    if (node >= nodeEnd) return;
    const int g = lane & 15, p = lane >> 4;
    const uint4 qv = *(const uint4*)&Qh[(size_t)node * 128 + g * 8];
    const h2f q0 = u2h(qv.x), q1 = u2h(qv.y), q2 = u2h(qv.z), q3 = u2h(qv.w);
    const int e0 = row_ptr[node], e1 = row_ptr[node + 1];
    const int cnt = e1 - e0;
    const int e1m1 = e1 - 1;
    float a0 = 0.f, a1 = 0.f, a2 = 0.f, a3 = 0.f;
    float a4 = 0.f, a5 = 0.f, a6 = 0.f, a7 = 0.f, z = 0.f;
    for (int base = 0; base < cnt; base += 64) {
        const int nb = min(cnt - base, 64);
        const int eb = e0 + base + p;
        {
            const int s0 = esrc[min(eb, e1m1)];
            const unsigned char* r = KV + (size_t)((unsigned)s0 * 384u);
            const int s1 = esrc[min(eb + 4, e1m1)];
            const unsigned char* rB = KV + (size_t)((unsigned)s1 * 384u);
            uint4 kvA = *(const uint4*)(r + g * 16);
            uint2 vvA = *(const uint2*)(r + 256 + g * 8);
            uint4 kvB = *(const uint4*)(rB + g * 16);
            uint2 vvB = *(const uint2*)(rB + 256 + g * 8);
            for (int j = 0; j < nb; j += 8) {
                {   // group A: edges j..j+3
                    const uint4 kc = kvA; const uint2 vc = vvA;
                    if (j + 8 < nb) {                    // wave-uniform
                        const int sn = esrc[min(eb + j + 8, e1m1)];
                        const unsigned char* rn = KV + (size_t)((unsigned)sn * 384u);
                        kvA = *(const uint4*)(rn + g * 16);
                        vvA = *(const uint2*)(rn + 256 + g * 8);
                    }
                    EA_ACC(kc, vc, j + p);
                }
                {   // group B: edges j+4..j+7 (masked if beyond nb)
                    const uint4 kc = kvB; const uint2 vc = vvB;
                    if (j + 12 < nb) {                   // wave-uniform
                        const int sn = esrc[min(eb + j + 12, e1m1)];
                        const unsigned char* rn = KV + (size_t)((unsigned)sn * 384u);
                        kvB = *(const uint4*)(rn + g * 16);
                        vvB = *(const uint2*)(rn + 256 + g * 8);
                    }
                    EA_ACC(kc, vc, j + 4 + p);
                }
            }
        }
    }
    a0 += __shfl_xor(a0, 16); a0 += __shfl_xor(a0, 32);
    a1 += __shfl_xor(a1, 16); a1 += __shfl_xor(a1, 32);
    a2 += __shfl_xor(a2, 16); a2 += __shfl_xor(a2, 32);
    a3 += __shfl_xor(a3, 16); a3 += __shfl_xor(a3, 32);
    a4 += __shfl_xor(a4, 16); a4 += __shfl_xor(a4, 32);
    a5 += __shfl_xor(a5, 16); a5 += __shfl_xor(a5, 32);
    a6 += __shfl_xor(a6, 16); a6 += __shfl_xor(a6, 32);
    a7 += __shfl_xor(a7, 16); a7 += __shfl_xor(a7, 32);
    z  += __shfl_xor(z, 16);  z  += __shfl_xor(z, 32);
    const float inv = 1.f / (z * VSCALE);
    const float c = 128.f * z;
    if (p == 0) {
        uint4 o;
        o.x = pk2((a0 - c) * inv, (a1 - c) * inv);
        o.y = pk2((a2 - c) * inv, (a3 - c) * inv);
        o.z = pk2((a4 - c) * inv, (a5 - c) * inv);
        o.w = pk2((a6 - c) * inv, (a7 - c) * inv);
        *(uint4*)&attnb[(size_t)node * 128 + g * 8] = o;
    }
}

// ============================ BN apply (folds finalize) ====================
__global__ __launch_bounds__(256) void bn_apply_b_k(const unsigned short* __restrict__ X,
                                                    const float* __restrict__ rstats,
                                                    const float* __restrict__ gma,
                                                    const float* __restrict__ bta,
                                                    float invN, int total8,
                                                    float* __restrict__ out)
{
    __shared__ float aff[256];
    if (threadIdx.x < 128) {
        const int c = threadIdx.x;
        const float mu = rstats[c] * invN;
        const float var = rstats[128 + c] * invN - mu * mu;
        const float isg = rsqrtf(var + EPS) * gma[c];
        aff[c] = isg;
        aff[128 + c] = bta[c] - mu * isg;
    }
    __syncthreads();
    for (int i = blockIdx.x * blockDim.x + threadIdx.x; i < total8;
         i += gridDim.x * blockDim.x) {
        const int c8 = (i & 15) * 8;
        const float4 sc0 = *(const float4*)&aff[c8];
        const float4 sc1 = *(const float4*)&aff[c8 + 4];
        const float4 sh0 = *(const float4*)&aff[128 + c8];
        const float4 sh1 = *(const float4*)&aff[128 + c8 + 4];
        const uint4 v = ((const uint4*)X)[i];
        float4 o0, o1;
        o0.x = b2f((unsigned short)(v.x & 0xffff)) * sc0.x + sh0.x;
        o0.y = b2f((unsigned short)(v.x >> 16))    * sc0.y + sh0.y;
        o0.z = b2f((unsigned short)(v.y & 0xffff)) * sc0.z + sh0.z;
        o0.w = b2f((unsigned short)(v.y >> 16))    * sc0.w + sh0.w;
        o1.x = b2f((unsigned short)(v.z & 0xffff)) * sc1.x + sh1.x;
        o1.y = b2f((unsigned short)(v.z >> 16))    * sc1.y + sh1.y;
        o1.z = b2f((unsigned short)(v.w & 0xffff)) * sc1.z + sh1.z;
        o1.w = b2f((unsigned short)(v.w >> 16))    * sc1.w + sh1.w;
        ((float4*)out)[i * 2]     = o0;
        ((float4*)out)[i * 2 + 1] = o1;
    }
}

// ============================ launch =======================================
extern "C" void kernel_launch(void* const* d_in, const int* in_sizes, int n_in,
                              void* d_out, int out_size, void* d_ws, size_t ws_size,
                              hipStream_t stream)
{
    const float* h   = (const float*)d_in[0];
    const float* Wq  = (const float*)d_in[1];
    const float* Wk  = (const float*)d_in[2];
    const float* Wv  = (const float*)d_in[3];
    const float* Wo  = (const float*)d_in[4];
    const float* bo  = (const float*)d_in[5];
    const float* g1  = (const float*)d_in[6];
    const float* b1  = (const float*)d_in[7];
    const float* Wf1 = (const float*)d_in[8];
    const float* bf1 = (const float*)d_in[9];
    const float* Wf2 = (const float*)d_in[10];
    const float* bf2 = (const float*)d_in[11];
    const float* g2  = (const float*)d_in[12];
    const float* b2  = (const float*)d_in[13];
    const int*   src = (const int*)d_in[14];
    const int*   dstv= (const int*)d_in[15];
    const int N = in_sizes[0] / 128;
    const int E = in_sizes[14];
    const int B = (N + 255) >> 8;
    const float invN = 1.f / (float)N;

    // ---- workspace layout ----
    unsigned short* Wt = (unsigned short*)d_ws;               // 131072 bf16
    float* stats1 = (float*)((char*)d_ws + 262144);           // 256
    float* stats2 = stats1 + 256;                             // 256
    int* bCnt = (int*)(stats2 + 256);                         // 512
    int* bOff = bCnt + 512;                                   // 513
    int* bCur = bOff + 513;                                   // 512
    uintptr_t big = ((uintptr_t)(bCur + 512) + 255) & ~(uintptr_t)255;
    _Float16* Qh = (_Float16*)big;                            // N*128 f16  (N*256B)
    unsigned char* KV = (unsigned char*)(Qh + (size_t)N * 128);   // N*384B packed K|V
    uintptr_t a2 = ((uintptr_t)(KV + (size_t)N * 384) + 255) & ~(uintptr_t)255;
    unsigned short* attnb = (unsigned short*)a2;              // N*128 bf16
    unsigned short* xb = attnb + (size_t)N * 128;             // N*128 bf16
    int* row_ptr = (int*)(xb + (size_t)N * 128);              // N+1
    // overlays (lifetimes disjoint):
    unsigned* coarse = (unsigned*)attnb;   // CSR temp; attnb born at edge_attn
    int* esrc = (int*)xb;                  // CSR out; xb born at Wo-GEMM
    unsigned short* hidden = (unsigned short*)Qh;  // N*256 bf16 (N*512B over Qh+KV head)
    unsigned short* yb = attnb;            // FFN2 bf16 out; attnb dead after Wo-GEMM
    // fold outputs: past hidden end, inside Qh+KV region (KV dead after edge_attn)
    uintptr_t fb = (big + (size_t)N * 512 + 255) & ~(uintptr_t)255;
    float* aff1 = (float*)fb;                          // 256 f
    float* b1f  = aff1 + 256;                          // 256 f
    unsigned short* W1f = (unsigned short*)(b1f + 256);// 256*128 bf16 (64KB)

    unsigned short* Wf1T = Wt + 65536;
    unsigned short* Wf2T = Wt + 98304;

    float* out = (float*)d_out;
    const dim3 b256(256);
    const dim3 b512(512);
    const int tiles64 = (N + 63) / 64;
    const int tiles32 = (N + 31) / 32;

    hipMemsetAsync(stats1, 0, 4096, stream);

    // ---- weight prep ----
    prep_all_k<<<dim3(512), b256, 0, stream>>>(Wq, Wk, Wv, Wo, Wf1, Wf2, Wt);

    // ---- CSR build ----
    bucket_cnt_k<<<dim3(256), b256, 0, stream>>>(dstv, E, bCnt);
    bucket_scan_k<<<dim3(1), dim3(512), 0, stream>>>(bCnt, B, bOff, bCur);
    coarse_k<<<dim3((E + CCH - 1) / CCH), dim3(512), 0, stream>>>(src, dstv, E, bCur, coarse);
    fine_k<<<dim3(B), b256, 0, stream>>>(coarse, bOff, B, N, row_ptr, esrc);

    // ---- fused QKV (persistent gemm, W in regs; capacity-matched grid) ----
    qkv3_k<<<dim3(171, 3), b512, 0, stream>>>(h, Wt, Qh, KV, N, tiles64);

    // ---- sparse attention -> attnb bf16 (3-way node split for profiling) ----
    {
        const int c1 = ((N / 3) + 3) & ~3;
        const int c2 = ((2 * N / 3) + 3) & ~3;
        edge_attn_k<<<dim3((c1 + 3) / 4), b256, 0, stream>>>(
            Qh, KV, row_ptr, esrc, attnb, 0, c1);
        edge_attn_k<<<dim3((c2 - c1 + 3) / 4), b256, 0, stream>>>(
            Qh, KV, row_ptr, esrc, attnb, c1, c2);
        edge_attn_k<<<dim3((N - c2 + 3) / 4), b256, 0, stream>>>(
            Qh, KV, row_ptr, esrc, attnb, c2, N);
    }

    // ---- x = h + attn @ Wo + bo (bf16 out) ; BN1 raw moments ----
    gemm3_k<128, 1, 1, 0><<<dim3(512, 1), b512, 0, stream>>>(
        attnb, Wt + 49152, bo, h, xb, N, 128, tiles64, nullptr, stats1);

    // ---- fold BN1 into FFN1 weights; emit aff1 for FFN2 resid ----
    fold_bn1_k<<<dim3(1), b256, 0, stream>>>(Wf1T, stats1, g1, b1, bf1, invN,
                                             W1f, b1f, aff1);

    // ---- FFN1: plain GEMM on raw x with folded weights, relu ----
    gemm3_k<128, 0, 0, 1><<<dim3(256, 2), b512, 0, stream>>>(
        xb, W1f, b1f, nullptr, hidden, N, 256, tiles64, nullptr, nullptr);

    // ---- FFN2: resid = BN1(x) via aff1; BN2 raw moments -> yb bf16 ----
    gemm3_k<256, 3, 1, 0><<<dim3(512, 1), b512, 0, stream>>>(
        hidden, Wf2T, bf2, xb, yb, N, 128, tiles32, aff1, stats2);

    // ---- BN2 apply (finalize folded): yb bf16 -> out fp32 ----
    bn_apply_b_k<<<dim3(1024), b256, 0, stream>>>(yb, stats2, g2, b2, invN, N * 16, out);
}

// Round 10
// 468.198 us; speedup vs baseline: 1.0074x; 1.0074x over previous
//
#include <hip/hip_runtime.h>

#define EPS 1e-5f
#define VSCALE 20.0f

typedef __attribute__((ext_vector_type(8))) short sh8;
typedef __attribute__((ext_vector_type(4))) float f4;
typedef __attribute__((ext_vector_type(2))) _Float16 h2f;

static __device__ __forceinline__ unsigned short f2b(float f) {
    union { float f; unsigned u; } v; v.f = f;
    unsigned r = v.u + 0x7FFF + ((v.u >> 16) & 1);  // RNE
    return (unsigned short)(r >> 16);
}
static __device__ __forceinline__ float b2f(unsigned short b) {
    union { unsigned u; float f; } v; v.u = ((unsigned)b) << 16; return v.f;
}
static __device__ __forceinline__ unsigned pk2(float a, float b) {
    return (unsigned)f2b(a) | ((unsigned)f2b(b) << 16);
}
static __device__ __forceinline__ h2f u2h(unsigned u) {
    union { unsigned u; h2f h; } c; c.u = u; return c.h;
}
static __device__ __forceinline__ float dot2h(h2f a, h2f b, float c) {
#if __has_builtin(__builtin_amdgcn_fdot2)
    return __builtin_amdgcn_fdot2(a, b, c, false);
#else
    return (float)a.x * (float)b.x + (float)a.y * (float)b.y + c;
#endif
}
// u8 lane extracts as float (v_cvt_f32_ubyteN when available)
#if __has_builtin(__builtin_amdgcn_cvt_f32_ubyte0)
#define UB0(x) __builtin_amdgcn_cvt_f32_ubyte0(x)
#define UB1(x) __builtin_amdgcn_cvt_f32_ubyte1(x)
#define UB2(x) __builtin_amdgcn_cvt_f32_ubyte2(x)
#define UB3(x) __builtin_amdgcn_cvt_f32_ubyte3(x)
#else
#define UB0(x) ((float)((x) & 0xffu))
#define UB1(x) ((float)(((x) >> 8) & 0xffu))
#define UB2(x) ((float)(((x) >> 16) & 0xffu))
#define UB3(x) ((float)((x) >> 24))
#endif

// raw barrier: lgkmcnt-only (never drains vmcnt -> prefetch stays in flight)
static __device__ __forceinline__ void barrier_raw() {
    __builtin_amdgcn_sched_barrier(0);
    asm volatile("s_waitcnt lgkmcnt(0)" ::: "memory");
    __builtin_amdgcn_s_barrier();
    __builtin_amdgcn_sched_barrier(0);
}

// ===================== weight prep (all 6, one launch) =====================
__global__ __launch_bounds__(256) void prep_all_k(
    const float* __restrict__ Wq, const float* __restrict__ Wk,
    const float* __restrict__ Wv, const float* __restrict__ Wo,
    const float* __restrict__ Wf1, const float* __restrict__ Wf2,
    unsigned short* __restrict__ Wt)
{
    int i = blockIdx.x * 256 + threadIdx.x;      // 0..131071
    if (i < 65536) {
        int s = i >> 14;
        const float* W = (s == 0) ? Wq : (s == 1) ? Wk : (s == 2) ? Wv : Wo;
        int l = i & 16383, k = l >> 7, n = l & 127;
        Wt[(i & ~16383) + n * 128 + k] = f2b(W[l]);
    } else if (i < 98304) {
        int l = i - 65536, k = l >> 8, n = l & 255;
        Wt[65536 + n * 128 + k] = f2b(Wf1[l]);
    } else {
        int l = i - 98304, k = l >> 7, n = l & 127;
        Wt[98304 + n * 256 + k] = f2b(Wf2[l]);
    }
}

// ===================== QKV: persistent streaming GEMM, W in registers ======
// (512,4): VGPR ~52, 32KB LDS -> 4 blocks/CU resident with a >=1024-block grid.
__global__ __launch_bounds__(512, 4) void qkv3_k(
    const float* __restrict__ h, const unsigned short* __restrict__ Wt,
    _Float16* __restrict__ Qh, unsigned char* __restrict__ KV,
    int M, int tiles)
{
    constexpr int KD = 128, PER = 2;
    __shared__ __align__(16) unsigned short As[2][64 * KD];
    const int tid = threadIdx.x;
    const int wave = tid >> 6, lane = tid & 63;
    const int q = lane >> 4, lm = lane & 15;
    const int wr = wave >> 2, wc = wave & 3;     // 2 row-halves x 4 col-quarters
    const int wv = blockIdx.y;                   // 0=Q 1=K 2=V
    const unsigned short* Wblk = Wt + (size_t)wv * 16384;

    // ---- prologue A prefetch (fp32, 2 float4 per chunk) ----
    float4 rAf[PER][2];
    {
        const int rowT = blockIdx.x * 64;
#pragma unroll
        for (int i = 0; i < PER; ++i) {
            int g = tid + i * 512;
            int row = g >> 4, ch = g & 15;
            int grow = rowT + row; if (grow >= M) grow = M - 1;
            const float* p = &h[(size_t)grow * 128 + ch * 8];
            rAf[i][0] = *(const float4*)p;
            rAf[i][1] = *(const float4*)(p + 4);
        }
    }

    // ---- W fragments -> registers (once) ----
    sh8 wfr[2][4];
#pragma unroll
    for (int ni = 0; ni < 2; ++ni)
#pragma unroll
        for (int kc = 0; kc < 4; ++kc)
            wfr[ni][kc] = *(const sh8*)&Wblk[(size_t)(wc * 32 + ni * 16 + lm) * KD
                                             + (kc * 4 + q) * 8];

    int cur = 0;
    for (int t = blockIdx.x; t < tiles; t += gridDim.x) {
        const int rowT = t * 64;
        barrier_raw();                        // As[cur] free
        unsigned short* Asc = As[cur];
#pragma unroll
        for (int i = 0; i < PER; ++i) {       // convert + write (waits via dep)
            int g = tid + i * 512;
            int row = g >> 4, ch = g & 15;
            uint4 v;
            v.x = pk2(rAf[i][0].x, rAf[i][0].y);
            v.y = pk2(rAf[i][0].z, rAf[i][0].w);
            v.z = pk2(rAf[i][1].x, rAf[i][1].y);
            v.w = pk2(rAf[i][1].z, rAf[i][1].w);
            *(uint4*)&Asc[row * KD + ((ch ^ (row & 7)) * 8)] = v;
        }
        const int tn = t + (int)gridDim.x;
        if (tn < tiles) {                     // issue next prefetch NOW
            const int rowTn = tn * 64;
#pragma unroll
            for (int i = 0; i < PER; ++i) {
                int g = tid + i * 512;
                int row = g >> 4, ch = g & 15;
                int grow = rowTn + row; if (grow >= M) grow = M - 1;
                const float* p = &h[(size_t)grow * 128 + ch * 8];
                rAf[i][0] = *(const float4*)p;
                rAf[i][1] = *(const float4*)(p + 4);
            }
        }
        barrier_raw();                        // As[cur] visible

        f4 acc[2][2];
#pragma unroll
        for (int mi = 0; mi < 2; ++mi)
#pragma unroll
            for (int ni = 0; ni < 2; ++ni) {
                f4 z = {0.f, 0.f, 0.f, 0.f};
                acc[mi][ni] = z;
            }
#pragma unroll
        for (int kc = 0; kc < 4; ++kc) {
            sh8 af[2];
#pragma unroll
            for (int mi = 0; mi < 2; ++mi) {
                const int row = wr * 32 + mi * 16 + lm;
                af[mi] = *(const sh8*)&Asc[row * KD + (((kc * 4 + q) ^ (row & 7)) * 8)];
            }
#pragma unroll
            for (int mi = 0; mi < 2; ++mi)
#pragma unroll
                for (int ni = 0; ni < 2; ++ni)
                    acc[mi][ni] = __builtin_amdgcn_mfma_f32_16x16x32_bf16(
                        af[mi], wfr[ni][kc], acc[mi][ni], 0, 0, 0);
        }

        // ---- epilogue ----
#pragma unroll
        for (int ni = 0; ni < 2; ++ni) {
            const int col = wc * 32 + ni * 16 + lm;
#pragma unroll
            for (int mi = 0; mi < 2; ++mi) {
#pragma unroll
                for (int r = 0; r < 4; ++r) {
                    const int row = rowT + wr * 32 + mi * 16 + q * 4 + r;
                    if (row >= M) continue;
                    const float v = acc[mi][ni][r];
                    if (wv == 0) Qh[(size_t)row * 128 + col] = (_Float16)v;
                    else if (wv == 1)
                        *(_Float16*)(KV + (size_t)row * 384 + col * 2) = (_Float16)v;
                    else {
                        float tt = rintf(v * VSCALE);
                        tt = fminf(fmaxf(tt, -127.f), 127.f);
                        KV[(size_t)row * 384 + 256 + col] = (unsigned char)(int)(tt + 128.f);
                    }
                }
            }
        }
        cur ^= 1;
    }
}

// ========== persistent streaming GEMM, W in registers ======================
// Geometry per KD keeps VGPR <= 128 (no spill at (512,4)):
//  KD=128: 64-row tiles, waves 2x4 (32 cols each), wfr[2][4]=32 VGPR.
//  KD=256: 32-row tiles, waves 1x8 (16 cols each), wfr[1][8]=32 VGPR.
// As = 32KB both -> 4 blocks/CU resident with >=1024-block grids.
template<int KD, int RES, int STATS, int RELU>
__global__ __launch_bounds__(512, 4) void gemm3_k(
    const unsigned short* __restrict__ A, const unsigned short* __restrict__ Wt,
    const float* __restrict__ bias, const void* __restrict__ resid,
    unsigned short* __restrict__ C, int M, int ldc, int tiles,
    const float* __restrict__ aff1, float* __restrict__ ostats)
{
    constexpr int CPR = KD / 8;               // 16B chunks per row
    constexpr int NWC = (KD == 128) ? 4 : 8;  // wave-columns
    constexpr int NI  = (KD == 128) ? 2 : 1;  // 16-col fragments per wave
    constexpr int TM  = (KD == 128) ? 64 : 32;// rows per tile
    constexpr int PER = TM * CPR / 512;       // staged chunks per thread
    constexpr int KC  = KD / 32;              // mfma K-steps
    __shared__ __align__(16) unsigned short As[2][TM * KD];
    __shared__ float sacc[256];
    const int tid = threadIdx.x;
    const int wave = tid >> 6, lane = tid & 63;
    const int q = lane >> 4, lm = lane & 15;
    const int wr = wave / NWC, wc = wave % NWC;
    const int colBase = blockIdx.y * 128;
    const unsigned short* Wblk = Wt + (size_t)colBase * KD;

    // ---- prologue A prefetch (issue first) ----
    uint4 rA[PER];
    {
        const int rowT = blockIdx.x * TM;
#pragma unroll
        for (int i = 0; i < PER; ++i) {
            int g = tid + i * 512;
            int row = g / CPR, ch = g % CPR;
            int grow = rowT + row; if (grow >= M) grow = M - 1;
            rA[i] = *(const uint4*)&A[(size_t)grow * KD + ch * 8];
        }
    }

    // ---- W fragments -> registers (once) ----
    sh8 wfr[NI][KC];
#pragma unroll
    for (int ni = 0; ni < NI; ++ni)
#pragma unroll
        for (int kc = 0; kc < KC; ++kc)
            wfr[ni][kc] = *(const sh8*)&Wblk[(size_t)(wc * (16 * NI) + ni * 16 + lm) * KD
                                             + (kc * 4 + q) * 8];
    if (STATS && tid < 256) sacc[tid] = 0.f;

    // ---- per-lane epilogue constants ----
    float bv[NI], rsc[NI], rsh[NI];
#pragma unroll
    for (int ni = 0; ni < NI; ++ni) {
        const int col = colBase + wc * (16 * NI) + ni * 16 + lm;
        bv[ni] = bias[col];
        if (RES == 3) { rsc[ni] = aff1[col]; rsh[ni] = aff1[128 + col]; }
        else { rsc[ni] = 0.f; rsh[ni] = 0.f; }
    }
    float st_s[NI], st_ss[NI];
#pragma unroll
    for (int ni = 0; ni < NI; ++ni) { st_s[ni] = 0.f; st_ss[ni] = 0.f; }

    int cur = 0;
    for (int t = blockIdx.x; t < tiles; t += gridDim.x) {
        const int rowT = t * TM;
        barrier_raw();                        // As[cur] free
        unsigned short* Asc = As[cur];
#pragma unroll
        for (int i = 0; i < PER; ++i) {       // waits vmcnt via rA register dep
            int g = tid + i * 512;
            int row = g / CPR, ch = g % CPR;
            *(uint4*)&Asc[row * KD + ((ch ^ (row & 7)) * 8)] = rA[i];
        }
        const int tn = t + (int)gridDim.x;
        if (tn < tiles) {                     // issue next prefetch NOW
            const int rowTn = tn * TM;
#pragma unroll
            for (int i = 0; i < PER; ++i) {
                int g = tid + i * 512;
                int row = g / CPR, ch = g % CPR;
                int grow = rowTn + row; if (grow >= M) grow = M - 1;
                rA[i] = *(const uint4*)&A[(size_t)grow * KD + ch * 8];
            }
        }
        barrier_raw();                        // As[cur] visible

        f4 acc[2][NI];
#pragma unroll
        for (int mi = 0; mi < 2; ++mi)
#pragma unroll
            for (int ni = 0; ni < NI; ++ni) {
                f4 z = {0.f, 0.f, 0.f, 0.f};
                acc[mi][ni] = z;
            }
#pragma unroll
        for (int kc = 0; kc < KC; ++kc) {
            sh8 af[2];
#pragma unroll
            for (int mi = 0; mi < 2; ++mi) {
                const int row = wr * 32 + mi * 16 + lm;
                af[mi] = *(const sh8*)&Asc[row * KD + (((kc * 4 + q) ^ (row & 7)) * 8)];
            }
#pragma unroll
            for (int mi = 0; mi < 2; ++mi)
#pragma unroll
                for (int ni = 0; ni < NI; ++ni)
                    acc[mi][ni] = __builtin_amdgcn_mfma_f32_16x16x32_bf16(
                        af[mi], wfr[ni][kc], acc[mi][ni], 0, 0, 0);
        }

        // ---- epilogue (per-lane, round-0 numerics) ----
#pragma unroll
        for (int ni = 0; ni < NI; ++ni) {
            const int col = colBase + wc * (16 * NI) + ni * 16 + lm;
#pragma unroll
            for (int mi = 0; mi < 2; ++mi) {
#pragma unroll
                for (int r = 0; r < 4; ++r) {
                    const int row = rowT + wr * 32 + mi * 16 + q * 4 + r;
                    if (row >= M) continue;
                    float val = acc[mi][ni][r] + bv[ni];
                    if (RES == 1)
                        val += ((const float*)resid)[(size_t)row * ldc + col];
                    if (RES == 3)
                        val += b2f(((const unsigned short*)resid)[(size_t)row * ldc + col])
                               * rsc[ni] + rsh[ni];
                    if (RELU) val = fmaxf(val, 0.f);
                    if (STATS) { st_s[ni] += val; st_ss[ni] += val * val; }
                    C[(size_t)row * ldc + col] = f2b(val);
                }
            }
        }
        cur ^= 1;
    }

    // ---- stats tail ----
    if (STATS) {
        barrier_raw();
#pragma unroll
        for (int ni = 0; ni < NI; ++ni) {
            st_s[ni]  += __shfl_xor(st_s[ni], 16);  st_s[ni]  += __shfl_xor(st_s[ni], 32);
            st_ss[ni] += __shfl_xor(st_ss[ni], 16); st_ss[ni] += __shfl_xor(st_ss[ni], 32);
            if (q == 0) {
                const int c = wc * (16 * NI) + ni * 16 + lm;
                atomicAdd(&sacc[c], st_s[ni]);
                atomicAdd(&sacc[128 + c], st_ss[ni]);
            }
        }
        barrier_raw();
        if (tid < 128) {
            atomicAdd(&ostats[tid], sacc[tid]);
            atomicAdd(&ostats[128 + tid], sacc[128 + tid]);
        }
    }
}

// ============== BN1 fold into FFN1 weights =================================
__global__ __launch_bounds__(256) void fold_bn1_k(
    const unsigned short* __restrict__ W1t, const float* __restrict__ rstats,
    const float* __restrict__ g1, const float* __restrict__ b1,
    const float* __restrict__ bf1, float invN,
    unsigned short* __restrict__ W1f, float* __restrict__ b1f,
    float* __restrict__ aff1)
{
    __shared__ float sc[128], sh[128];
    const int t = threadIdx.x;
    if (t < 128) {
        const float mu = rstats[t] * invN;
        const float var = rstats[128 + t] * invN - mu * mu;
        const float isg = rsqrtf(var + EPS) * g1[t];
        const float shf = b1[t] - mu * isg;
        sc[t] = isg; sh[t] = shf;
        aff1[t] = isg; aff1[128 + t] = shf;
    }
    __syncthreads();
    float acc = bf1[t];
#pragma unroll
    for (int c = 0; c < 128; c += 8) {
        const uint4 v = *(const uint4*)&W1t[t * 128 + c];
        const float w0 = b2f((unsigned short)(v.x & 0xffff));
        const float w1 = b2f((unsigned short)(v.x >> 16));
        const float w2 = b2f((unsigned short)(v.y & 0xffff));
        const float w3 = b2f((unsigned short)(v.y >> 16));
        const float w4 = b2f((unsigned short)(v.z & 0xffff));
        const float w5 = b2f((unsigned short)(v.z >> 16));
        const float w6 = b2f((unsigned short)(v.w & 0xffff));
        const float w7 = b2f((unsigned short)(v.w >> 16));
        acc += sh[c] * w0 + sh[c + 1] * w1 + sh[c + 2] * w2 + sh[c + 3] * w3
             + sh[c + 4] * w4 + sh[c + 5] * w5 + sh[c + 6] * w6 + sh[c + 7] * w7;
        uint4 o;
        o.x = pk2(w0 * sc[c],     w1 * sc[c + 1]);
        o.y = pk2(w2 * sc[c + 2], w3 * sc[c + 3]);
        o.z = pk2(w4 * sc[c + 4], w5 * sc[c + 5]);
        o.w = pk2(w6 * sc[c + 6], w7 * sc[c + 7]);
        *(uint4*)&W1f[t * 128 + c] = o;
    }
    b1f[t] = acc;
}

// ============== CSR build: two-level LDS counting sort =====================
__global__ __launch_bounds__(256) void bucket_cnt_k(const int* __restrict__ dst,
                                                    int E, int* __restrict__ bCnt)
{
    __shared__ int c[512];
    const int t = threadIdx.x;
    c[t] = 0; c[t + 256] = 0;
    __syncthreads();
    for (int i = blockIdx.x * 256 + t; i < E; i += gridDim.x * 256)
        atomicAdd(&c[dst[i] >> 8], 1);
    __syncthreads();
    if (c[t]) atomicAdd(&bCnt[t], c[t]);
    if (c[t + 256]) atomicAdd(&bCnt[t + 256], c[t + 256]);
}

__global__ __launch_bounds__(512) void bucket_scan_k(const int* __restrict__ bCnt,
                                                     int B, int* __restrict__ bOff,
                                                     int* __restrict__ bCur)
{
    __shared__ int ts[512];
    const int t = threadIdx.x;
    const int v = (t < B) ? bCnt[t] : 0;
    ts[t] = v;
    __syncthreads();
    for (int o = 1; o < 512; o <<= 1) {
        int u = (t >= o) ? ts[t - o] : 0;
        __syncthreads();
        ts[t] += u;
        __syncthreads();
    }
    const int ex = ts[t] - v;
    if (t < B) { bOff[t] = ex; bCur[t] = ex; }
    if (t == B - 1) bOff[B] = ex + v;
}

#define CCH 8192
__global__ __launch_bounds__(512) void coarse_k(const int* __restrict__ src,
                                                const int* __restrict__ dst, int E,
                                                int* __restrict__ bCur,
                                                unsigned* __restrict__ coarse)
{
    __shared__ int cnt[512], off[512], gbase[512], rc[512];
    __shared__ unsigned pk[CCH];
    __shared__ int ga[CCH];
    const int t = threadIdx.x;
    const int e0 = blockIdx.x * CCH;
    const int n = min(CCH, E - e0);
    cnt[t] = 0;
    __syncthreads();
    for (int i = t; i < n; i += 512) atomicAdd(&cnt[dst[e0 + i] >> 8], 1);
    __syncthreads();
    const int v = cnt[t];
    off[t] = v;
    __syncthreads();
    for (int o = 1; o < 512; o <<= 1) {
        int u = (t >= o) ? off[t - o] : 0;
        __syncthreads();
        off[t] += u;
        __syncthreads();
    }
    const int ex = off[t] - v;
    off[t] = ex;
    if (v > 0) gbase[t] = atomicAdd(&bCur[t], v);
    rc[t] = 0;
    __syncthreads();
    for (int i = t; i < n; i += 512) {
        const int d = dst[e0 + i], s = src[e0 + i];
        const int b = d >> 8;
        const int j = atomicAdd(&rc[b], 1);
        const int slot = off[b] + j;
        pk[slot] = ((unsigned)(d & 255) << 17) | (unsigned)s;
        ga[slot] = gbase[b] + j;
    }
    __syncthreads();
    for (int i = t; i < n; i += 512) coarse[ga[i]] = pk[i];
}

__global__ __launch_bounds__(256) void fine_k(const unsigned* __restrict__ coarse,
                                              const int* __restrict__ bOff, int B,
                                              int Nn, int* __restrict__ row_ptr,
                                              int* __restrict__ esrc)
{
    __shared__ int cnt[256], off[256], rc[256];
    const int t = threadIdx.x;
    const int b = blockIdx.x;
    const int base = b << 8;
    const int e0 = bOff[b], e1 = bOff[b + 1];
    cnt[t] = 0;
    __syncthreads();
    for (int i = e0 + t; i < e1; i += 256)
        atomicAdd(&cnt[(coarse[i] >> 17) & 255], 1);
    __syncthreads();
    const int v = cnt[t];
    off[t] = v;
    __syncthreads();
    for (int o = 1; o < 256; o <<= 1) {
        int u = (t >= o) ? off[t - o] : 0;
        __syncthreads();
        off[t] += u;
        __syncthreads();
    }
    const int ex = off[t] - v;
    off[t] = ex;
    rc[t] = 0;
    if (base + t < Nn) row_ptr[base + t] = e0 + ex;
    if (b == B - 1 && t == 0) row_ptr[Nn] = e1;
    __syncthreads();
    for (int i = e0 + t; i < e1; i += 256) {
        const unsigned p = coarse[i];
        const int l = (p >> 17) & 255;
        const int j = atomicAdd(&rc[l], 1);
        esrc[e0 + off[l] + j] = (int)(p & 0x1FFFFu);
    }
}

// ============================ edge attention ===============================
#define EA_ACC(kc, vc, EI) do {                                              \
    float sp = dot2h(u2h((kc).w), q3, dot2h(u2h((kc).z), q2,                 \
               dot2h(u2h((kc).y), q1, dot2h(u2h((kc).x), q0, 0.f))));        \
    sp += __shfl_xor(sp, 1);                                                 \
    float sc = __expf(fminf(fmaxf(sp * 0.25f, -5.f), 5.f));                  \
    sc = ((EI) < nb) ? sc : 0.f;                                             \
    a0 += sc * UB0((vc).x);                                                  \
    a1 += sc * UB1((vc).x);                                                  \
    a2 += sc * UB2((vc).x);                                                  \
    a3 += sc * UB3((vc).x);                                                  \
    a4 += sc * UB0((vc).y);                                                  \
    a5 += sc * UB1((vc).y);                                                  \
    a6 += sc * UB2((vc).y);                                                  \
    a7 += sc * UB3((vc).y);                                                  \
    z += sc;                                                                 \
} while (0)

__global__ __launch_bounds__(256) void edge_attn_k(
    const _Float16* __restrict__ Qh, const unsigned char* __restrict__ KV,
    const int* __restrict__ row_ptr, const int* __restrict__ esrc,
    unsigned short* __restrict__ attnb, int nodeOff, int nodeEnd)
{
    const int wave = threadIdx.x >> 6, lane = threadIdx.x & 63;
    const int node = nodeOff + blockIdx.x * 4 + wave;
    if (node >= nodeEnd) return;
    const int g = lane & 15, p = lane >> 4;
    const uint4 qv = *(const uint4*)&Qh[(size_t)node * 128 + g * 8];
    const h2f q0 = u2h(qv.x), q1 = u2h(qv.y), q2 = u2h(qv.z), q3 = u2h(qv.w);
    const int e0 = row_ptr[node], e1 = row_ptr[node + 1];
    const int cnt = e1 - e0;
    const int e1m1 = e1 - 1;
    float a0 = 0.f, a1 = 0.f, a2 = 0.f, a3 = 0.f;
    float a4 = 0.f, a5 = 0.f, a6 = 0.f, a7 = 0.f, z = 0.f;
    for (int base = 0; base < cnt; base += 64) {
        const int nb = min(cnt - base, 64);
        const int eb = e0 + base + p;
        {
            const int s0 = esrc[min(eb, e1m1)];
            const unsigned char* r = KV + (size_t)((unsigned)s0 * 384u);
            const int s1 = esrc[min(eb + 4, e1m1)];
            const unsigned char* rB = KV + (size_t)((unsigned)s1 * 384u);
            uint4 kvA = *(const uint4*)(r + g * 16);
            uint2 vvA = *(const uint2*)(r + 256 + g * 8);
            uint4 kvB = *(const uint4*)(rB + g * 16);
            uint2 vvB = *(const uint2*)(rB + 256 + g * 8);
            for (int j = 0; j < nb; j += 8) {
                {   // group A: edges j..j+3
                    const uint4 kc = kvA; const uint2 vc = vvA;
                    if (j + 8 < nb) {                    // wave-uniform
                        const int sn = esrc[min(eb + j + 8, e1m1)];
                        const unsigned char* rn = KV + (size_t)((unsigned)sn * 384u);
                        kvA = *(const uint4*)(rn + g * 16);
                        vvA = *(const uint2*)(rn + 256 + g * 8);
                    }
                    EA_ACC(kc, vc, j + p);
                }
                {   // group B: edges j+4..j+7 (masked if beyond nb)
                    const uint4 kc = kvB; const uint2 vc = vvB;
                    if (j + 12 < nb) {                   // wave-uniform
                        const int sn = esrc[min(eb + j + 12, e1m1)];
                        const unsigned char* rn = KV + (size_t)((unsigned)sn * 384u);
                        kvB = *(const uint4*)(rn + g * 16);
                        vvB = *(const uint2*)(rn + 256 + g * 8);
                    }
                    EA_ACC(kc, vc, j + 4 + p);
                }
            }
        }
    }
    a0 += __shfl_xor(a0, 16); a0 += __shfl_xor(a0, 32);
    a1 += __shfl_xor(a1, 16); a1 += __shfl_xor(a1, 32);
    a2 += __shfl_xor(a2, 16); a2 += __shfl_xor(a2, 32);
    a3 += __shfl_xor(a3, 16); a3 += __shfl_xor(a3, 32);
    a4 += __shfl_xor(a4, 16); a4 += __shfl_xor(a4, 32);
    a5 += __shfl_xor(a5, 16); a5 += __shfl_xor(a5, 32);
    a6 += __shfl_xor(a6, 16); a6 += __shfl_xor(a6, 32);
    a7 += __shfl_xor(a7, 16); a7 += __shfl_xor(a7, 32);
    z  += __shfl_xor(z, 16);  z  += __shfl_xor(z, 32);
    const float inv = 1.f / (z * VSCALE);
    const float c = 128.f * z;
    if (p == 0) {
        uint4 o;
        o.x = pk2((a0 - c) * inv, (a1 - c) * inv);
        o.y = pk2((a2 - c) * inv, (a3 - c) * inv);
        o.z = pk2((a4 - c) * inv, (a5 - c) * inv);
        o.w = pk2((a6 - c) * inv, (a7 - c) * inv);
        *(uint4*)&attnb[(size_t)node * 128 + g * 8] = o;
    }
}

// ============================ BN apply (folds finalize) ====================
__global__ __launch_bounds__(256) void bn_apply_b_k(const unsigned short* __restrict__ X,
                                                    const float* __restrict__ rstats,
                                                    const float* __restrict__ gma,
                                                    const float* __restrict__ bta,
                                                    float invN, int total8,
                                                    float* __restrict__ out)
{
    __shared__ float aff[256];
    if (threadIdx.x < 128) {
        const int c = threadIdx.x;
        const float mu = rstats[c] * invN;
        const float var = rstats[128 + c] * invN - mu * mu;
        const float isg = rsqrtf(var + EPS) * gma[c];
        aff[c] = isg;
        aff[128 + c] = bta[c] - mu * isg;
    }
    __syncthreads();
    for (int i = blockIdx.x * blockDim.x + threadIdx.x; i < total8;
         i += gridDim.x * blockDim.x) {
        const int c8 = (i & 15) * 8;
        const float4 sc0 = *(const float4*)&aff[c8];
        const float4 sc1 = *(const float4*)&aff[c8 + 4];
        const float4 sh0 = *(const float4*)&aff[128 + c8];
        const float4 sh1 = *(const float4*)&aff[128 + c8 + 4];
        const uint4 v = ((const uint4*)X)[i];
        float4 o0, o1;
        o0.x = b2f((unsigned short)(v.x & 0xffff)) * sc0.x + sh0.x;
        o0.y = b2f((unsigned short)(v.x >> 16))    * sc0.y + sh0.y;
        o0.z = b2f((unsigned short)(v.y & 0xffff)) * sc0.z + sh0.z;
        o0.w = b2f((unsigned short)(v.y >> 16))    * sc0.w + sh0.w;
        o1.x = b2f((unsigned short)(v.z & 0xffff)) * sc1.x + sh1.x;
        o1.y = b2f((unsigned short)(v.z >> 16))    * sc1.y + sh1.y;
        o1.z = b2f((unsigned short)(v.w & 0xffff)) * sc1.z + sh1.z;
        o1.w = b2f((unsigned short)(v.w >> 16))    * sc1.w + sh1.w;
        ((float4*)out)[i * 2]     = o0;
        ((float4*)out)[i * 2 + 1] = o1;
    }
}

// ============================ launch =======================================
extern "C" void kernel_launch(void* const* d_in, const int* in_sizes, int n_in,
                              void* d_out, int out_size, void* d_ws, size_t ws_size,
                              hipStream_t stream)
{
    const float* h   = (const float*)d_in[0];
    const float* Wq  = (const float*)d_in[1];
    const float* Wk  = (const float*)d_in[2];
    const float* Wv  = (const float*)d_in[3];
    const float* Wo  = (const float*)d_in[4];
    const float* bo  = (const float*)d_in[5];
    const float* g1  = (const float*)d_in[6];
    const float* b1  = (const float*)d_in[7];
    const float* Wf1 = (const float*)d_in[8];
    const float* bf1 = (const float*)d_in[9];
    const float* Wf2 = (const float*)d_in[10];
    const float* bf2 = (const float*)d_in[11];
    const float* g2  = (const float*)d_in[12];
    const float* b2  = (const float*)d_in[13];
    const int*   src = (const int*)d_in[14];
    const int*   dstv= (const int*)d_in[15];
    const int N = in_sizes[0] / 128;
    const int E = in_sizes[14];
    const int B = (N + 255) >> 8;
    const float invN = 1.f / (float)N;

    // ---- workspace layout ----
    unsigned short* Wt = (unsigned short*)d_ws;               // 131072 bf16
    float* stats1 = (float*)((char*)d_ws + 262144);           // 256
    float* stats2 = stats1 + 256;                             // 256
    int* bCnt = (int*)(stats2 + 256);                         // 512
    int* bOff = bCnt + 512;                                   // 513
    int* bCur = bOff + 513;                                   // 512
    uintptr_t big = ((uintptr_t)(bCur + 512) + 255) & ~(uintptr_t)255;
    _Float16* Qh = (_Float16*)big;                            // N*128 f16  (N*256B)
    unsigned char* KV = (unsigned char*)(Qh + (size_t)N * 128);   // N*384B packed K|V
    uintptr_t a2 = ((uintptr_t)(KV + (size_t)N * 384) + 255) & ~(uintptr_t)255;
    unsigned short* attnb = (unsigned short*)a2;              // N*128 bf16
    unsigned short* xb = attnb + (size_t)N * 128;             // N*128 bf16
    int* row_ptr = (int*)(xb + (size_t)N * 128);              // N+1
    // overlays (lifetimes disjoint):
    unsigned* coarse = (unsigned*)attnb;   // CSR temp; attnb born at edge_attn
    int* esrc = (int*)xb;                  // CSR out; xb born at Wo-GEMM
    unsigned short* hidden = (unsigned short*)Qh;  // N*256 bf16 (N*512B over Qh+KV head)
    unsigned short* yb = attnb;            // FFN2 bf16 out; attnb dead after Wo-GEMM
    // fold outputs: past hidden end, inside Qh+KV region (KV dead after edge_attn)
    uintptr_t fb = (big + (size_t)N * 512 + 255) & ~(uintptr_t)255;
    float* aff1 = (float*)fb;                          // 256 f
    float* b1f  = aff1 + 256;                          // 256 f
    unsigned short* W1f = (unsigned short*)(b1f + 256);// 256*128 bf16 (64KB)

    unsigned short* Wf1T = Wt + 65536;
    unsigned short* Wf2T = Wt + 98304;

    float* out = (float*)d_out;
    const dim3 b256(256);
    const dim3 b512(512);
    const int tiles64 = (N + 63) / 64;
    const int tiles32 = (N + 31) / 32;

    hipMemsetAsync(stats1, 0, 4096, stream);

    // ---- weight prep ----
    prep_all_k<<<dim3(512), b256, 0, stream>>>(Wq, Wk, Wv, Wo, Wf1, Wf2, Wt);

    // ---- CSR build ----
    bucket_cnt_k<<<dim3(256), b256, 0, stream>>>(dstv, E, bCnt);
    bucket_scan_k<<<dim3(1), dim3(512), 0, stream>>>(bCnt, B, bOff, bCur);
    coarse_k<<<dim3((E + CCH - 1) / CCH), dim3(512), 0, stream>>>(src, dstv, E, bCur, coarse);
    fine_k<<<dim3(B), b256, 0, stream>>>(coarse, bOff, B, N, row_ptr, esrc);

    // ---- fused QKV (persistent gemm, W in regs; 4 blocks/CU grid) ----
    qkv3_k<<<dim3(341, 3), b512, 0, stream>>>(h, Wt, Qh, KV, N, tiles64);

    // ---- sparse attention -> attnb bf16 (single launch) ----
    edge_attn_k<<<dim3((N + 3) / 4), b256, 0, stream>>>(
        Qh, KV, row_ptr, esrc, attnb, 0, N);

    // ---- x = h + attn @ Wo + bo (bf16 out) ; BN1 raw moments ----
    gemm3_k<128, 1, 1, 0><<<dim3(1024, 1), b512, 0, stream>>>(
        attnb, Wt + 49152, bo, h, xb, N, 128, tiles64, nullptr, stats1);

    // ---- fold BN1 into FFN1 weights; emit aff1 for FFN2 resid ----
    fold_bn1_k<<<dim3(1), b256, 0, stream>>>(Wf1T, stats1, g1, b1, bf1, invN,
                                             W1f, b1f, aff1);

    // ---- FFN1: plain GEMM on raw x with folded weights, relu ----
    gemm3_k<128, 0, 0, 1><<<dim3(512, 2), b512, 0, stream>>>(
        xb, W1f, b1f, nullptr, hidden, N, 256, tiles64, nullptr, nullptr);

    // ---- FFN2: resid = BN1(x) via aff1; BN2 raw moments -> yb bf16 ----
    gemm3_k<256, 3, 1, 0><<<dim3(1024, 1), b512, 0, stream>>>(
        hidden, Wf2T, bf2, xb, yb, N, 128, tiles32, aff1, stats2);

    // ---- BN2 apply (finalize folded): yb bf16 -> out fp32 ----
    bn_apply_b_k<<<dim3(1024), b256, 0, stream>>>(yb, stats2, g2, b2, invN, N * 16, out);
}

// Round 11
// 440.736 us; speedup vs baseline: 1.0702x; 1.0623x over previous
//
#include <hip/hip_runtime.h>

#define EPS 1e-5f
#define VSCALE 20.0f

typedef __attribute__((ext_vector_type(8))) short sh8;
typedef __attribute__((ext_vector_type(4))) float f4;
typedef __attribute__((ext_vector_type(2))) _Float16 h2f;

static __device__ __forceinline__ unsigned short f2b(float f) {
    union { float f; unsigned u; } v; v.f = f;
    unsigned r = v.u + 0x7FFF + ((v.u >> 16) & 1);  // RNE
    return (unsigned short)(r >> 16);
}
static __device__ __forceinline__ float b2f(unsigned short b) {
    union { unsigned u; float f; } v; v.u = ((unsigned)b) << 16; return v.f;
}
static __device__ __forceinline__ unsigned pk2(float a, float b) {
    return (unsigned)f2b(a) | ((unsigned)f2b(b) << 16);
}
static __device__ __forceinline__ h2f u2h(unsigned u) {
    union { unsigned u; h2f h; } c; c.u = u; return c.h;
}
static __device__ __forceinline__ float dot2h(h2f a, h2f b, float c) {
#if __has_builtin(__builtin_amdgcn_fdot2)
    return __builtin_amdgcn_fdot2(a, b, c, false);
#else
    return (float)a.x * (float)b.x + (float)a.y * (float)b.y + c;
#endif
}
// u8 lane extracts as float (v_cvt_f32_ubyteN when available)
#if __has_builtin(__builtin_amdgcn_cvt_f32_ubyte0)
#define UB0(x) __builtin_amdgcn_cvt_f32_ubyte0(x)
#define UB1(x) __builtin_amdgcn_cvt_f32_ubyte1(x)
#define UB2(x) __builtin_amdgcn_cvt_f32_ubyte2(x)
#define UB3(x) __builtin_amdgcn_cvt_f32_ubyte3(x)
#else
#define UB0(x) ((float)((x) & 0xffu))
#define UB1(x) ((float)(((x) >> 8) & 0xffu))
#define UB2(x) ((float)(((x) >> 16) & 0xffu))
#define UB3(x) ((float)((x) >> 24))
#endif

// raw barrier: lgkmcnt-only (never drains vmcnt -> prefetch stays in flight)
static __device__ __forceinline__ void barrier_raw() {
    __builtin_amdgcn_sched_barrier(0);
    asm volatile("s_waitcnt lgkmcnt(0)" ::: "memory");
    __builtin_amdgcn_s_barrier();
    __builtin_amdgcn_sched_barrier(0);
}

// ===================== weight prep (all 6, one launch) =====================
__global__ __launch_bounds__(256) void prep_all_k(
    const float* __restrict__ Wq, const float* __restrict__ Wk,
    const float* __restrict__ Wv, const float* __restrict__ Wo,
    const float* __restrict__ Wf1, const float* __restrict__ Wf2,
    unsigned short* __restrict__ Wt)
{
    int i = blockIdx.x * 256 + threadIdx.x;      // 0..131071
    if (i < 65536) {
        int s = i >> 14;
        const float* W = (s == 0) ? Wq : (s == 1) ? Wk : (s == 2) ? Wv : Wo;
        int l = i & 16383, k = l >> 7, n = l & 127;
        Wt[(i & ~16383) + n * 128 + k] = f2b(W[l]);
    } else if (i < 98304) {
        int l = i - 65536, k = l >> 8, n = l & 255;
        Wt[65536 + n * 128 + k] = f2b(Wf1[l]);
    } else {
        int l = i - 98304, k = l >> 7, n = l & 127;
        Wt[98304 + n * 256 + k] = f2b(Wf2[l]);
    }
}

// ===================== QKV: persistent streaming GEMM, W in registers ======
// (512,4): VGPR ~52, 32KB LDS. UNCHANGED from round 8 (verified).
__global__ __launch_bounds__(512, 4) void qkv3_k(
    const float* __restrict__ h, const unsigned short* __restrict__ Wt,
    _Float16* __restrict__ Qh, unsigned char* __restrict__ KV,
    int M, int tiles)
{
    constexpr int KD = 128, PER = 2;
    __shared__ __align__(16) unsigned short As[2][64 * KD];
    const int tid = threadIdx.x;
    const int wave = tid >> 6, lane = tid & 63;
    const int q = lane >> 4, lm = lane & 15;
    const int wr = wave >> 2, wc = wave & 3;     // 2 row-halves x 4 col-quarters
    const int wv = blockIdx.y;                   // 0=Q 1=K 2=V
    const unsigned short* Wblk = Wt + (size_t)wv * 16384;

    // ---- prologue A prefetch (fp32, 2 float4 per chunk) ----
    float4 rAf[PER][2];
    {
        const int rowT = blockIdx.x * 64;
#pragma unroll
        for (int i = 0; i < PER; ++i) {
            int g = tid + i * 512;
            int row = g >> 4, ch = g & 15;
            int grow = rowT + row; if (grow >= M) grow = M - 1;
            const float* p = &h[(size_t)grow * 128 + ch * 8];
            rAf[i][0] = *(const float4*)p;
            rAf[i][1] = *(const float4*)(p + 4);
        }
    }

    // ---- W fragments -> registers (once) ----
    sh8 wfr[2][4];
#pragma unroll
    for (int ni = 0; ni < 2; ++ni)
#pragma unroll
        for (int kc = 0; kc < 4; ++kc)
            wfr[ni][kc] = *(const sh8*)&Wblk[(size_t)(wc * 32 + ni * 16 + lm) * KD
                                             + (kc * 4 + q) * 8];

    int cur = 0;
    for (int t = blockIdx.x; t < tiles; t += gridDim.x) {
        const int rowT = t * 64;
        barrier_raw();                        // As[cur] free
        unsigned short* Asc = As[cur];
#pragma unroll
        for (int i = 0; i < PER; ++i) {       // convert + write (waits via dep)
            int g = tid + i * 512;
            int row = g >> 4, ch = g & 15;
            uint4 v;
            v.x = pk2(rAf[i][0].x, rAf[i][0].y);
            v.y = pk2(rAf[i][0].z, rAf[i][0].w);
            v.z = pk2(rAf[i][1].x, rAf[i][1].y);
            v.w = pk2(rAf[i][1].z, rAf[i][1].w);
            *(uint4*)&Asc[row * KD + ((ch ^ (row & 7)) * 8)] = v;
        }
        const int tn = t + (int)gridDim.x;
        if (tn < tiles) {                     // issue next prefetch NOW
            const int rowTn = tn * 64;
#pragma unroll
            for (int i = 0; i < PER; ++i) {
                int g = tid + i * 512;
                int row = g >> 4, ch = g & 15;
                int grow = rowTn + row; if (grow >= M) grow = M - 1;
                const float* p = &h[(size_t)grow * 128 + ch * 8];
                rAf[i][0] = *(const float4*)p;
                rAf[i][1] = *(const float4*)(p + 4);
            }
        }
        barrier_raw();                        // As[cur] visible

        f4 acc[2][2];
#pragma unroll
        for (int mi = 0; mi < 2; ++mi)
#pragma unroll
            for (int ni = 0; ni < 2; ++ni) {
                f4 z = {0.f, 0.f, 0.f, 0.f};
                acc[mi][ni] = z;
            }
#pragma unroll
        for (int kc = 0; kc < 4; ++kc) {
            sh8 af[2];
#pragma unroll
            for (int mi = 0; mi < 2; ++mi) {
                const int row = wr * 32 + mi * 16 + lm;
                af[mi] = *(const sh8*)&Asc[row * KD + (((kc * 4 + q) ^ (row & 7)) * 8)];
            }
#pragma unroll
            for (int mi = 0; mi < 2; ++mi)
#pragma unroll
                for (int ni = 0; ni < 2; ++ni)
                    acc[mi][ni] = __builtin_amdgcn_mfma_f32_16x16x32_bf16(
                        af[mi], wfr[ni][kc], acc[mi][ni], 0, 0, 0);
        }

        // ---- epilogue ----
#pragma unroll
        for (int ni = 0; ni < 2; ++ni) {
            const int col = wc * 32 + ni * 16 + lm;
#pragma unroll
            for (int mi = 0; mi < 2; ++mi) {
#pragma unroll
                for (int r = 0; r < 4; ++r) {
                    const int row = rowT + wr * 32 + mi * 16 + q * 4 + r;
                    if (row >= M) continue;
                    const float v = acc[mi][ni][r];
                    if (wv == 0) Qh[(size_t)row * 128 + col] = (_Float16)v;
                    else if (wv == 1)
                        *(_Float16*)(KV + (size_t)row * 384 + col * 2) = (_Float16)v;
                    else {
                        float tt = rintf(v * VSCALE);
                        tt = fminf(fmaxf(tt, -127.f), 127.f);
                        KV[(size_t)row * 384 + 256 + col] = (unsigned char)(int)(tt + 128.f);
                    }
                }
            }
        }
        cur ^= 1;
    }
}

// ========== persistent streaming GEMM, W in regs, PACKED epilogue ==========
// MFMA operands swapped (mfma(wfr, af)): D transposes so each lane owns 4
// CONSECUTIVE COLS (q*4+r) of one row (lm). Same per-element sums/order ->
// identical f32 values; stores become uint2 (8B), resid reads float4/uint2.
//  KD=128: 64-row tiles, waves 2x4, NI=2.  KD=256: 32-row tiles, 1x8, NI=1.
template<int KD, int RES, int STATS, int RELU>
__global__ __launch_bounds__(512, 4) void gemm3_k(
    const unsigned short* __restrict__ A, const unsigned short* __restrict__ Wt,
    const float* __restrict__ bias, const void* __restrict__ resid,
    unsigned short* __restrict__ C, int M, int ldc, int tiles,
    const float* __restrict__ aff1, float* __restrict__ ostats)
{
    constexpr int CPR = KD / 8;               // 16B chunks per row
    constexpr int NWC = (KD == 128) ? 4 : 8;  // wave-columns
    constexpr int NI  = (KD == 128) ? 2 : 1;  // 16-col fragments per wave
    constexpr int TM  = (KD == 128) ? 64 : 32;// rows per tile
    constexpr int PER = TM * CPR / 512;       // staged chunks per thread
    constexpr int KC  = KD / 32;              // mfma K-steps
    __shared__ __align__(16) unsigned short As[2][TM * KD];
    __shared__ float sacc[256];
    const int tid = threadIdx.x;
    const int wave = tid >> 6, lane = tid & 63;
    const int q = lane >> 4, lm = lane & 15;
    const int wr = wave / NWC, wc = wave % NWC;
    const int colBase = blockIdx.y * 128;
    const unsigned short* Wblk = Wt + (size_t)colBase * KD;

    // ---- prologue A prefetch (issue first) ----
    uint4 rA[PER];
    {
        const int rowT = blockIdx.x * TM;
#pragma unroll
        for (int i = 0; i < PER; ++i) {
            int g = tid + i * 512;
            int row = g / CPR, ch = g % CPR;
            int grow = rowT + row; if (grow >= M) grow = M - 1;
            rA[i] = *(const uint4*)&A[(size_t)grow * KD + ch * 8];
        }
    }

    // ---- W fragments -> registers (once) ----
    sh8 wfr[NI][KC];
#pragma unroll
    for (int ni = 0; ni < NI; ++ni)
#pragma unroll
        for (int kc = 0; kc < KC; ++kc)
            wfr[ni][kc] = *(const sh8*)&Wblk[(size_t)(wc * (16 * NI) + ni * 16 + lm) * KD
                                             + (kc * 4 + q) * 8];
    if (STATS && tid < 256) sacc[tid] = 0.f;

    // ---- per-lane epilogue constants: 4 consecutive cols per ni ----
    float4 bv4[NI], rsc4[NI], rsh4[NI];
#pragma unroll
    for (int ni = 0; ni < NI; ++ni) {
        const int col0 = colBase + wc * (16 * NI) + ni * 16 + q * 4;
        bv4[ni] = *(const float4*)&bias[col0];
        if (RES == 3) {
            rsc4[ni] = *(const float4*)&aff1[col0];
            rsh4[ni] = *(const float4*)&aff1[128 + col0];
        } else {
            rsc4[ni] = make_float4(0.f, 0.f, 0.f, 0.f);
            rsh4[ni] = make_float4(0.f, 0.f, 0.f, 0.f);
        }
    }
    f4 st_s[NI], st_ss[NI];
#pragma unroll
    for (int ni = 0; ni < NI; ++ni) {
        f4 z = {0.f, 0.f, 0.f, 0.f};
        st_s[ni] = z; st_ss[ni] = z;
    }

    int cur = 0;
    for (int t = blockIdx.x; t < tiles; t += gridDim.x) {
        const int rowT = t * TM;
        barrier_raw();                        // As[cur] free
        unsigned short* Asc = As[cur];
#pragma unroll
        for (int i = 0; i < PER; ++i) {       // waits vmcnt via rA register dep
            int g = tid + i * 512;
            int row = g / CPR, ch = g % CPR;
            *(uint4*)&Asc[row * KD + ((ch ^ (row & 7)) * 8)] = rA[i];
        }
        const int tn = t + (int)gridDim.x;
        if (tn < tiles) {                     // issue next prefetch NOW
            const int rowTn = tn * TM;
#pragma unroll
            for (int i = 0; i < PER; ++i) {
                int g = tid + i * 512;
                int row = g / CPR, ch = g % CPR;
                int grow = rowTn + row; if (grow >= M) grow = M - 1;
                rA[i] = *(const uint4*)&A[(size_t)grow * KD + ch * 8];
            }
        }
        barrier_raw();                        // As[cur] visible

        f4 acc[2][NI];
#pragma unroll
        for (int mi = 0; mi < 2; ++mi)
#pragma unroll
            for (int ni = 0; ni < NI; ++ni) {
                f4 z = {0.f, 0.f, 0.f, 0.f};
                acc[mi][ni] = z;
            }
#pragma unroll
        for (int kc = 0; kc < KC; ++kc) {
            sh8 af[2];
#pragma unroll
            for (int mi = 0; mi < 2; ++mi) {
                const int row = wr * 32 + mi * 16 + lm;
                af[mi] = *(const sh8*)&Asc[row * KD + (((kc * 4 + q) ^ (row & 7)) * 8)];
            }
#pragma unroll
            for (int mi = 0; mi < 2; ++mi)
#pragma unroll
                for (int ni = 0; ni < NI; ++ni)
                    acc[mi][ni] = __builtin_amdgcn_mfma_f32_16x16x32_bf16(
                        wfr[ni][kc], af[mi], acc[mi][ni], 0, 0, 0);
        }

        // ---- packed epilogue: lane owns row (lm), cols col0..col0+3 ----
#pragma unroll
        for (int mi = 0; mi < 2; ++mi) {
            const int row = rowT + wr * 32 + mi * 16 + lm;
            if (row >= M) continue;
#pragma unroll
            for (int ni = 0; ni < NI; ++ni) {
                const int col0 = colBase + wc * (16 * NI) + ni * 16 + q * 4;
                const size_t rb = (size_t)row * ldc + col0;
                const f4 a = acc[mi][ni];
                float v0 = a[0] + bv4[ni].x, v1 = a[1] + bv4[ni].y;
                float v2 = a[2] + bv4[ni].z, v3 = a[3] + bv4[ni].w;
                if (RES == 1) {
                    const float4 rv = *(const float4*)&((const float*)resid)[rb];
                    v0 += rv.x; v1 += rv.y; v2 += rv.z; v3 += rv.w;
                }
                if (RES == 3) {
                    const uint2 rv = *(const uint2*)&((const unsigned short*)resid)[rb];
                    v0 += b2f((unsigned short)(rv.x & 0xffff)) * rsc4[ni].x + rsh4[ni].x;
                    v1 += b2f((unsigned short)(rv.x >> 16))    * rsc4[ni].y + rsh4[ni].y;
                    v2 += b2f((unsigned short)(rv.y & 0xffff)) * rsc4[ni].z + rsh4[ni].z;
                    v3 += b2f((unsigned short)(rv.y >> 16))    * rsc4[ni].w + rsh4[ni].w;
                }
                if (RELU) {
                    v0 = fmaxf(v0, 0.f); v1 = fmaxf(v1, 0.f);
                    v2 = fmaxf(v2, 0.f); v3 = fmaxf(v3, 0.f);
                }
                if (STATS) {
                    st_s[ni][0] += v0; st_s[ni][1] += v1;
                    st_s[ni][2] += v2; st_s[ni][3] += v3;
                    st_ss[ni][0] += v0 * v0; st_ss[ni][1] += v1 * v1;
                    st_ss[ni][2] += v2 * v2; st_ss[ni][3] += v3 * v3;
                }
                uint2 o;
                o.x = pk2(v0, v1); o.y = pk2(v2, v3);
                *(uint2*)&C[rb] = o;
            }
        }
        cur ^= 1;
    }

    // ---- stats tail: reduce over lm (shfl 1/2/4/8), lm==0 lanes atomics ----
    if (STATS) {
        barrier_raw();
#pragma unroll
        for (int ni = 0; ni < NI; ++ni) {
#pragma unroll
            for (int m = 1; m <= 8; m <<= 1) {
#pragma unroll
                for (int r = 0; r < 4; ++r) {
                    st_s[ni][r]  += __shfl_xor(st_s[ni][r], m);
                    st_ss[ni][r] += __shfl_xor(st_ss[ni][r], m);
                }
            }
            if (lm == 0) {
                const int col0 = wc * (16 * NI) + ni * 16 + q * 4;
#pragma unroll
                for (int r = 0; r < 4; ++r) {
                    atomicAdd(&sacc[col0 + r], st_s[ni][r]);
                    atomicAdd(&sacc[128 + col0 + r], st_ss[ni][r]);
                }
            }
        }
        barrier_raw();
        if (tid < 128) {
            atomicAdd(&ostats[tid], sacc[tid]);
            atomicAdd(&ostats[128 + tid], sacc[128 + tid]);
        }
    }
}

// ============== BN1 fold into FFN1 weights =================================
__global__ __launch_bounds__(256) void fold_bn1_k(
    const unsigned short* __restrict__ W1t, const float* __restrict__ rstats,
    const float* __restrict__ g1, const float* __restrict__ b1,
    const float* __restrict__ bf1, float invN,
    unsigned short* __restrict__ W1f, float* __restrict__ b1f,
    float* __restrict__ aff1)
{
    __shared__ float sc[128], sh[128];
    const int t = threadIdx.x;
    if (t < 128) {
        const float mu = rstats[t] * invN;
        const float var = rstats[128 + t] * invN - mu * mu;
        const float isg = rsqrtf(var + EPS) * g1[t];
        const float shf = b1[t] - mu * isg;
        sc[t] = isg; sh[t] = shf;
        aff1[t] = isg; aff1[128 + t] = shf;
    }
    __syncthreads();
    float acc = bf1[t];
#pragma unroll
    for (int c = 0; c < 128; c += 8) {
        const uint4 v = *(const uint4*)&W1t[t * 128 + c];
        const float w0 = b2f((unsigned short)(v.x & 0xffff));
        const float w1 = b2f((unsigned short)(v.x >> 16));
        const float w2 = b2f((unsigned short)(v.y & 0xffff));
        const float w3 = b2f((unsigned short)(v.y >> 16));
        const float w4 = b2f((unsigned short)(v.z & 0xffff));
        const float w5 = b2f((unsigned short)(v.z >> 16));
        const float w6 = b2f((unsigned short)(v.w & 0xffff));
        const float w7 = b2f((unsigned short)(v.w >> 16));
        acc += sh[c] * w0 + sh[c + 1] * w1 + sh[c + 2] * w2 + sh[c + 3] * w3
             + sh[c + 4] * w4 + sh[c + 5] * w5 + sh[c + 6] * w6 + sh[c + 7] * w7;
        uint4 o;
        o.x = pk2(w0 * sc[c],     w1 * sc[c + 1]);
        o.y = pk2(w2 * sc[c + 2], w3 * sc[c + 3]);
        o.z = pk2(w4 * sc[c + 4], w5 * sc[c + 5]);
        o.w = pk2(w6 * sc[c + 6], w7 * sc[c + 7]);
        *(uint4*)&W1f[t * 128 + c] = o;
    }
    b1f[t] = acc;
}

// ============== CSR build: two-level LDS counting sort =====================
__global__ __launch_bounds__(256) void bucket_cnt_k(const int* __restrict__ dst,
                                                    int E, int* __restrict__ bCnt)
{
    __shared__ int c[512];
    const int t = threadIdx.x;
    c[t] = 0; c[t + 256] = 0;
    __syncthreads();
    for (int i = blockIdx.x * 256 + t; i < E; i += gridDim.x * 256)
        atomicAdd(&c[dst[i] >> 8], 1);
    __syncthreads();
    if (c[t]) atomicAdd(&bCnt[t], c[t]);
    if (c[t + 256]) atomicAdd(&bCnt[t + 256], c[t + 256]);
}

__global__ __launch_bounds__(512) void bucket_scan_k(const int* __restrict__ bCnt,
                                                     int B, int* __restrict__ bOff,
                                                     int* __restrict__ bCur)
{
    __shared__ int ts[512];
    const int t = threadIdx.x;
    const int v = (t < B) ? bCnt[t] : 0;
    ts[t] = v;
    __syncthreads();
    for (int o = 1; o < 512; o <<= 1) {
        int u = (t >= o) ? ts[t - o] : 0;
        __syncthreads();
        ts[t] += u;
        __syncthreads();
    }
    const int ex = ts[t] - v;
    if (t < B) { bOff[t] = ex; bCur[t] = ex; }
    if (t == B - 1) bOff[B] = ex + v;
}

#define CCH 8192
__global__ __launch_bounds__(512) void coarse_k(const int* __restrict__ src,
                                                const int* __restrict__ dst, int E,
                                                int* __restrict__ bCur,
                                                unsigned* __restrict__ coarse)
{
    __shared__ int cnt[512], off[512], gbase[512], rc[512];
    __shared__ unsigned pk[CCH];
    __shared__ int ga[CCH];
    const int t = threadIdx.x;
    const int e0 = blockIdx.x * CCH;
    const int n = min(CCH, E - e0);
    cnt[t] = 0;
    __syncthreads();
    for (int i = t; i < n; i += 512) atomicAdd(&cnt[dst[e0 + i] >> 8], 1);
    __syncthreads();
    const int v = cnt[t];
    off[t] = v;
    __syncthreads();
    for (int o = 1; o < 512; o <<= 1) {
        int u = (t >= o) ? off[t - o] : 0;
        __syncthreads();
        off[t] += u;
        __syncthreads();
    }
    const int ex = off[t] - v;
    off[t] = ex;
    if (v > 0) gbase[t] = atomicAdd(&bCur[t], v);
    rc[t] = 0;
    __syncthreads();
    for (int i = t; i < n; i += 512) {
        const int d = dst[e0 + i], s = src[e0 + i];
        const int b = d >> 8;
        const int j = atomicAdd(&rc[b], 1);
        const int slot = off[b] + j;
        pk[slot] = ((unsigned)(d & 255) << 17) | (unsigned)s;
        ga[slot] = gbase[b] + j;
    }
    __syncthreads();
    for (int i = t; i < n; i += 512) coarse[ga[i]] = pk[i];
}

__global__ __launch_bounds__(256) void fine_k(const unsigned* __restrict__ coarse,
                                              const int* __restrict__ bOff, int B,
                                              int Nn, int* __restrict__ row_ptr,
                                              int* __restrict__ esrc)
{
    __shared__ int cnt[256], off[256], rc[256];
    const int t = threadIdx.x;
    const int b = blockIdx.x;
    const int base = b << 8;
    const int e0 = bOff[b], e1 = bOff[b + 1];
    cnt[t] = 0;
    __syncthreads();
    for (int i = e0 + t; i < e1; i += 256)
        atomicAdd(&cnt[(coarse[i] >> 17) & 255], 1);
    __syncthreads();
    const int v = cnt[t];
    off[t] = v;
    __syncthreads();
    for (int o = 1; o < 256; o <<= 1) {
        int u = (t >= o) ? off[t - o] : 0;
        __syncthreads();
        off[t] += u;
        __syncthreads();
    }
    const int ex = off[t] - v;
    off[t] = ex;
    rc[t] = 0;
    if (base + t < Nn) row_ptr[base + t] = e0 + ex;
    if (b == B - 1 && t == 0) row_ptr[Nn] = e1;
    __syncthreads();
    for (int i = e0 + t; i < e1; i += 256) {
        const unsigned p = coarse[i];
        const int l = (p >> 17) & 255;
        const int j = atomicAdd(&rc[l], 1);
        esrc[e0 + off[l] + j] = (int)(p & 0x1FFFFu);
    }
}

// ============================ edge attention ===============================
#define EA_ACC(kc, vc, EI) do {                                              \
    float sp = dot2h(u2h((kc).w), q3, dot2h(u2h((kc).z), q2,                 \
               dot2h(u2h((kc).y), q1, dot2h(u2h((kc).x), q0, 0.f))));        \
    sp += __shfl_xor(sp, 1);                                                 \
    float sc = __expf(fminf(fmaxf(sp * 0.25f, -5.f), 5.f));                  \
    sc = ((EI) < nb) ? sc : 0.f;                                             \
    a0 += sc * UB0((vc).x);                                                  \
    a1 += sc * UB1((vc).x);                                                  \
    a2 += sc * UB2((vc).x);                                                  \
    a3 += sc * UB3((vc).x);                                                  \
    a4 += sc * UB0((vc).y);                                                  \
    a5 += sc * UB1((vc).y);                                                  \
    a6 += sc * UB2((vc).y);                                                  \
    a7 += sc * UB3((vc).y);                                                  \
    z += sc;                                                                 \
} while (0)

__global__ __launch_bounds__(256) void edge_attn_k(
    const _Float16* __restrict__ Qh, const unsigned char* __restrict__ KV,
    const int* __restrict__ row_ptr, const int* __restrict__ esrc,
    unsigned short* __restrict__ attnb, int nodeOff, int nodeEnd)
{
    const int wave = threadIdx.x >> 6, lane = threadIdx.x & 63;
    const int node = nodeOff + blockIdx.x * 4 + wave;
    if (node >= nodeEnd) return;
    const int g = lane & 15, p = lane >> 4;
    const uint4 qv = *(const uint4*)&Qh[(size_t)node * 128 + g * 8];
    const h2f q0 = u2h(qv.x), q1 = u2h(qv.y), q2 = u2h(qv.z), q3 = u2h(qv.w);
    const int e0 = row_ptr[node], e1 = row_ptr[node + 1];
    const int cnt = e1 - e0;
    const int e1m1 = e1 - 1;
    float a0 = 0.f, a1 = 0.f, a2 = 0.f, a3 = 0.f;
    float a4 = 0.f, a5 = 0.f, a6 = 0.f, a7 = 0.f, z = 0.f;
    for (int base = 0; base < cnt; base += 64) {
        const int nb = min(cnt - base, 64);
        const int eb = e0 + base + p;
        {
            const int s0 = esrc[min(eb, e1m1)];
            const unsigned char* r = KV + (size_t)((unsigned)s0 * 384u);
            const int s1 = esrc[min(eb + 4, e1m1)];
            const unsigned char* rB = KV + (size_t)((unsigned)s1 * 384u);
            uint4 kvA = *(const uint4*)(r + g * 16);
            uint2 vvA = *(const uint2*)(r + 256 + g * 8);
            uint4 kvB = *(const uint4*)(rB + g * 16);
            uint2 vvB = *(const uint2*)(rB + 256 + g * 8);
            for (int j = 0; j < nb; j += 8) {
                {   // group A: edges j..j+3
                    const uint4 kc = kvA; const uint2 vc = vvA;
                    if (j + 8 < nb) {                    // wave-uniform
                        const int sn = esrc[min(eb + j + 8, e1m1)];
                        const unsigned char* rn = KV + (size_t)((unsigned)sn * 384u);
                        kvA = *(const uint4*)(rn + g * 16);
                        vvA = *(const uint2*)(rn + 256 + g * 8);
                    }
                    EA_ACC(kc, vc, j + p);
                }
                {   // group B: edges j+4..j+7 (masked if beyond nb)
                    const uint4 kc = kvB; const uint2 vc = vvB;
                    if (j + 12 < nb) {                   // wave-uniform
                        const int sn = esrc[min(eb + j + 12, e1m1)];
                        const unsigned char* rn = KV + (size_t)((unsigned)sn * 384u);
                        kvB = *(const uint4*)(rn + g * 16);
                        vvB = *(const uint2*)(rn + 256 + g * 8);
                    }
                    EA_ACC(kc, vc, j + 4 + p);
                }
            }
        }
    }
    a0 += __shfl_xor(a0, 16); a0 += __shfl_xor(a0, 32);
    a1 += __shfl_xor(a1, 16); a1 += __shfl_xor(a1, 32);
    a2 += __shfl_xor(a2, 16); a2 += __shfl_xor(a2, 32);
    a3 += __shfl_xor(a3, 16); a3 += __shfl_xor(a3, 32);
    a4 += __shfl_xor(a4, 16); a4 += __shfl_xor(a4, 32);
    a5 += __shfl_xor(a5, 16); a5 += __shfl_xor(a5, 32);
    a6 += __shfl_xor(a6, 16); a6 += __shfl_xor(a6, 32);
    a7 += __shfl_xor(a7, 16); a7 += __shfl_xor(a7, 32);
    z  += __shfl_xor(z, 16);  z  += __shfl_xor(z, 32);
    const float inv = 1.f / (z * VSCALE);
    const float c = 128.f * z;
    if (p == 0) {
        uint4 o;
        o.x = pk2((a0 - c) * inv, (a1 - c) * inv);
        o.y = pk2((a2 - c) * inv, (a3 - c) * inv);
        o.z = pk2((a4 - c) * inv, (a5 - c) * inv);
        o.w = pk2((a6 - c) * inv, (a7 - c) * inv);
        *(uint4*)&attnb[(size_t)node * 128 + g * 8] = o;
    }
}

// ============================ BN apply (folds finalize) ====================
__global__ __launch_bounds__(256) void bn_apply_b_k(const unsigned short* __restrict__ X,
                                                    const float* __restrict__ rstats,
                                                    const float* __restrict__ gma,
                                                    const float* __restrict__ bta,
                                                    float invN, int total8,
                                                    float* __restrict__ out)
{
    __shared__ float aff[256];
    if (threadIdx.x < 128) {
        const int c = threadIdx.x;
        const float mu = rstats[c] * invN;
        const float var = rstats[128 + c] * invN - mu * mu;
        const float isg = rsqrtf(var + EPS) * gma[c];
        aff[c] = isg;
        aff[128 + c] = bta[c] - mu * isg;
    }
    __syncthreads();
    for (int i = blockIdx.x * blockDim.x + threadIdx.x; i < total8;
         i += gridDim.x * blockDim.x) {
        const int c8 = (i & 15) * 8;
        const float4 sc0 = *(const float4*)&aff[c8];
        const float4 sc1 = *(const float4*)&aff[c8 + 4];
        const float4 sh0 = *(const float4*)&aff[128 + c8];
        const float4 sh1 = *(const float4*)&aff[128 + c8 + 4];
        const uint4 v = ((const uint4*)X)[i];
        float4 o0, o1;
        o0.x = b2f((unsigned short)(v.x & 0xffff)) * sc0.x + sh0.x;
        o0.y = b2f((unsigned short)(v.x >> 16))    * sc0.y + sh0.y;
        o0.z = b2f((unsigned short)(v.y & 0xffff)) * sc0.z + sh0.z;
        o0.w = b2f((unsigned short)(v.y >> 16))    * sc0.w + sh0.w;
        o1.x = b2f((unsigned short)(v.z & 0xffff)) * sc1.x + sh1.x;
        o1.y = b2f((unsigned short)(v.z >> 16))    * sc1.y + sh1.y;
        o1.z = b2f((unsigned short)(v.w & 0xffff)) * sc1.z + sh1.z;
        o1.w = b2f((unsigned short)(v.w >> 16))    * sc1.w + sh1.w;
        ((float4*)out)[i * 2]     = o0;
        ((float4*)out)[i * 2 + 1] = o1;
    }
}

// ============================ launch =======================================
extern "C" void kernel_launch(void* const* d_in, const int* in_sizes, int n_in,
                              void* d_out, int out_size, void* d_ws, size_t ws_size,
                              hipStream_t stream)
{
    const float* h   = (const float*)d_in[0];
    const float* Wq  = (const float*)d_in[1];
    const float* Wk  = (const float*)d_in[2];
    const float* Wv  = (const float*)d_in[3];
    const float* Wo  = (const float*)d_in[4];
    const float* bo  = (const float*)d_in[5];
    const float* g1  = (const float*)d_in[6];
    const float* b1  = (const float*)d_in[7];
    const float* Wf1 = (const float*)d_in[8];
    const float* bf1 = (const float*)d_in[9];
    const float* Wf2 = (const float*)d_in[10];
    const float* bf2 = (const float*)d_in[11];
    const float* g2  = (const float*)d_in[12];
    const float* b2  = (const float*)d_in[13];
    const int*   src = (const int*)d_in[14];
    const int*   dstv= (const int*)d_in[15];
    const int N = in_sizes[0] / 128;
    const int E = in_sizes[14];
    const int B = (N + 255) >> 8;
    const float invN = 1.f / (float)N;

    // ---- workspace layout ----
    unsigned short* Wt = (unsigned short*)d_ws;               // 131072 bf16
    float* stats1 = (float*)((char*)d_ws + 262144);           // 256
    float* stats2 = stats1 + 256;                             // 256
    int* bCnt = (int*)(stats2 + 256);                         // 512
    int* bOff = bCnt + 512;                                   // 513
    int* bCur = bOff + 513;                                   // 512
    uintptr_t big = ((uintptr_t)(bCur + 512) + 255) & ~(uintptr_t)255;
    _Float16* Qh = (_Float16*)big;                            // N*128 f16  (N*256B)
    unsigned char* KV = (unsigned char*)(Qh + (size_t)N * 128);   // N*384B packed K|V
    uintptr_t a2 = ((uintptr_t)(KV + (size_t)N * 384) + 255) & ~(uintptr_t)255;
    unsigned short* attnb = (unsigned short*)a2;              // N*128 bf16
    unsigned short* xb = attnb + (size_t)N * 128;             // N*128 bf16
    int* row_ptr = (int*)(xb + (size_t)N * 128);              // N+1
    // overlays (lifetimes disjoint):
    unsigned* coarse = (unsigned*)attnb;   // CSR temp; attnb born at edge_attn
    int* esrc = (int*)xb;                  // CSR out; xb born at Wo-GEMM
    unsigned short* hidden = (unsigned short*)Qh;  // N*256 bf16 (N*512B over Qh+KV head)
    unsigned short* yb = attnb;            // FFN2 bf16 out; attnb dead after Wo-GEMM
    // fold outputs: past hidden end, inside Qh+KV region (KV dead after edge_attn)
    uintptr_t fb = (big + (size_t)N * 512 + 255) & ~(uintptr_t)255;
    float* aff1 = (float*)fb;                          // 256 f
    float* b1f  = aff1 + 256;                          // 256 f
    unsigned short* W1f = (unsigned short*)(b1f + 256);// 256*128 bf16 (64KB)

    unsigned short* Wf1T = Wt + 65536;
    unsigned short* Wf2T = Wt + 98304;

    float* out = (float*)d_out;
    const dim3 b256(256);
    const dim3 b512(512);
    const int tiles64 = (N + 63) / 64;
    const int tiles32 = (N + 31) / 32;

    hipMemsetAsync(stats1, 0, 4096, stream);

    // ---- weight prep ----
    prep_all_k<<<dim3(512), b256, 0, stream>>>(Wq, Wk, Wv, Wo, Wf1, Wf2, Wt);

    // ---- CSR build ----
    bucket_cnt_k<<<dim3(256), b256, 0, stream>>>(dstv, E, bCnt);
    bucket_scan_k<<<dim3(1), dim3(512), 0, stream>>>(bCnt, B, bOff, bCur);
    coarse_k<<<dim3((E + CCH - 1) / CCH), dim3(512), 0, stream>>>(src, dstv, E, bCur, coarse);
    fine_k<<<dim3(B), b256, 0, stream>>>(coarse, bOff, B, N, row_ptr, esrc);

    // ---- fused QKV (persistent gemm, W in regs) ----
    qkv3_k<<<dim3(341, 3), b512, 0, stream>>>(h, Wt, Qh, KV, N, tiles64);

    // ---- sparse attention -> attnb bf16 (single launch) ----
    edge_attn_k<<<dim3((N + 3) / 4), b256, 0, stream>>>(
        Qh, KV, row_ptr, esrc, attnb, 0, N);

    // ---- x = h + attn @ Wo + bo (bf16 out) ; BN1 raw moments ----
    gemm3_k<128, 1, 1, 0><<<dim3(512, 1), b512, 0, stream>>>(
        attnb, Wt + 49152, bo, h, xb, N, 128, tiles64, nullptr, stats1);

    // ---- fold BN1 into FFN1 weights; emit aff1 for FFN2 resid ----
    fold_bn1_k<<<dim3(1), b256, 0, stream>>>(Wf1T, stats1, g1, b1, bf1, invN,
                                             W1f, b1f, aff1);

    // ---- FFN1: plain GEMM on raw x with folded weights, relu ----
    gemm3_k<128, 0, 0, 1><<<dim3(512, 2), b512, 0, stream>>>(
        xb, W1f, b1f, nullptr, hidden, N, 256, tiles64, nullptr, nullptr);

    // ---- FFN2: resid = BN1(x) via aff1; BN2 raw moments -> yb bf16 ----
    gemm3_k<256, 3, 1, 0><<<dim3(512, 1), b512, 0, stream>>>(
        hidden, Wf2T, bf2, xb, yb, N, 128, tiles32, aff1, stats2);

    // ---- BN2 apply (finalize folded): yb bf16 -> out fp32 ----
    bn_apply_b_k<<<dim3(1024), b256, 0, stream>>>(yb, stats2, g2, b2, invN, N * 16, out);
}

// Round 12
// 439.387 us; speedup vs baseline: 1.0735x; 1.0031x over previous
//
#include <hip/hip_runtime.h>

#define EPS 1e-5f
#define VSCALE 20.0f

typedef __attribute__((ext_vector_type(8))) short sh8;
typedef __attribute__((ext_vector_type(4))) float f4;
typedef __attribute__((ext_vector_type(2))) _Float16 h2f;

static __device__ __forceinline__ unsigned short f2b(float f) {
    union { float f; unsigned u; } v; v.f = f;
    unsigned r = v.u + 0x7FFF + ((v.u >> 16) & 1);  // RNE
    return (unsigned short)(r >> 16);
}
static __device__ __forceinline__ float b2f(unsigned short b) {
    union { unsigned u; float f; } v; v.u = ((unsigned)b) << 16; return v.f;
}
static __device__ __forceinline__ unsigned pk2(float a, float b) {
    return (unsigned)f2b(a) | ((unsigned)f2b(b) << 16);
}
static __device__ __forceinline__ h2f u2h(unsigned u) {
    union { unsigned u; h2f h; } c; c.u = u; return c.h;
}
static __device__ __forceinline__ unsigned pkh2(float a, float b) {
    union { h2f h; unsigned u; } c;
    c.h.x = (_Float16)a; c.h.y = (_Float16)b;
    return c.u;
}
static __device__ __forceinline__ float dot2h(h2f a, h2f b, float c) {
#if __has_builtin(__builtin_amdgcn_fdot2)
    return __builtin_amdgcn_fdot2(a, b, c, false);
#else
    return (float)a.x * (float)b.x + (float)a.y * (float)b.y + c;
#endif
}
// u8 lane extracts as float (v_cvt_f32_ubyteN when available)
#if __has_builtin(__builtin_amdgcn_cvt_f32_ubyte0)
#define UB0(x) __builtin_amdgcn_cvt_f32_ubyte0(x)
#define UB1(x) __builtin_amdgcn_cvt_f32_ubyte1(x)
#define UB2(x) __builtin_amdgcn_cvt_f32_ubyte2(x)
#define UB3(x) __builtin_amdgcn_cvt_f32_ubyte3(x)
#else
#define UB0(x) ((float)((x) & 0xffu))
#define UB1(x) ((float)(((x) >> 8) & 0xffu))
#define UB2(x) ((float)(((x) >> 16) & 0xffu))
#define UB3(x) ((float)((x) >> 24))
#endif

// raw barrier: lgkmcnt-only (never drains vmcnt -> prefetch stays in flight)
static __device__ __forceinline__ void barrier_raw() {
    __builtin_amdgcn_sched_barrier(0);
    asm volatile("s_waitcnt lgkmcnt(0)" ::: "memory");
    __builtin_amdgcn_s_barrier();
    __builtin_amdgcn_sched_barrier(0);
}

// ===================== weight prep (all 6, one launch) =====================
__global__ __launch_bounds__(256) void prep_all_k(
    const float* __restrict__ Wq, const float* __restrict__ Wk,
    const float* __restrict__ Wv, const float* __restrict__ Wo,
    const float* __restrict__ Wf1, const float* __restrict__ Wf2,
    unsigned short* __restrict__ Wt)
{
    int i = blockIdx.x * 256 + threadIdx.x;      // 0..131071
    if (i < 65536) {
        int s = i >> 14;
        const float* W = (s == 0) ? Wq : (s == 1) ? Wk : (s == 2) ? Wv : Wo;
        int l = i & 16383, k = l >> 7, n = l & 127;
        Wt[(i & ~16383) + n * 128 + k] = f2b(W[l]);
    } else if (i < 98304) {
        int l = i - 65536, k = l >> 8, n = l & 255;
        Wt[65536 + n * 128 + k] = f2b(Wf1[l]);
    } else {
        int l = i - 98304, k = l >> 7, n = l & 127;
        Wt[98304 + n * 256 + k] = f2b(Wf2[l]);
    }
}

// ===================== QKV: persistent streaming GEMM, W in regs ===========
// PACKED epilogue (operand-swapped MFMA, as verified in gemm3_k round 11):
// lane owns row (lm), 4 consecutive cols (q*4+r). Q/K: uint2 (4xf16 8B);
// V: one packed u32 (4 bytes). Same values/rounding -> bit-identical output.
__global__ __launch_bounds__(512, 4) void qkv3_k(
    const float* __restrict__ h, const unsigned short* __restrict__ Wt,
    _Float16* __restrict__ Qh, unsigned char* __restrict__ KV,
    int M, int tiles)
{
    constexpr int KD = 128, PER = 2;
    __shared__ __align__(16) unsigned short As[2][64 * KD];
    const int tid = threadIdx.x;
    const int wave = tid >> 6, lane = tid & 63;
    const int q = lane >> 4, lm = lane & 15;
    const int wr = wave >> 2, wc = wave & 3;     // 2 row-halves x 4 col-quarters
    const int wv = blockIdx.y;                   // 0=Q 1=K 2=V
    const unsigned short* Wblk = Wt + (size_t)wv * 16384;

    // ---- prologue A prefetch (fp32, 2 float4 per chunk) ----
    float4 rAf[PER][2];
    {
        const int rowT = blockIdx.x * 64;
#pragma unroll
        for (int i = 0; i < PER; ++i) {
            int g = tid + i * 512;
            int row = g >> 4, ch = g & 15;
            int grow = rowT + row; if (grow >= M) grow = M - 1;
            const float* p = &h[(size_t)grow * 128 + ch * 8];
            rAf[i][0] = *(const float4*)p;
            rAf[i][1] = *(const float4*)(p + 4);
        }
    }

    // ---- W fragments -> registers (once) ----
    sh8 wfr[2][4];
#pragma unroll
    for (int ni = 0; ni < 2; ++ni)
#pragma unroll
        for (int kc = 0; kc < 4; ++kc)
            wfr[ni][kc] = *(const sh8*)&Wblk[(size_t)(wc * 32 + ni * 16 + lm) * KD
                                             + (kc * 4 + q) * 8];

    int cur = 0;
    for (int t = blockIdx.x; t < tiles; t += gridDim.x) {
        const int rowT = t * 64;
        barrier_raw();                        // As[cur] free
        unsigned short* Asc = As[cur];
#pragma unroll
        for (int i = 0; i < PER; ++i) {       // convert + write (waits via dep)
            int g = tid + i * 512;
            int row = g >> 4, ch = g & 15;
            uint4 v;
            v.x = pk2(rAf[i][0].x, rAf[i][0].y);
            v.y = pk2(rAf[i][0].z, rAf[i][0].w);
            v.z = pk2(rAf[i][1].x, rAf[i][1].y);
            v.w = pk2(rAf[i][1].z, rAf[i][1].w);
            *(uint4*)&Asc[row * KD + ((ch ^ (row & 7)) * 8)] = v;
        }
        const int tn = t + (int)gridDim.x;
        if (tn < tiles) {                     // issue next prefetch NOW
            const int rowTn = tn * 64;
#pragma unroll
            for (int i = 0; i < PER; ++i) {
                int g = tid + i * 512;
                int row = g >> 4, ch = g & 15;
                int grow = rowTn + row; if (grow >= M) grow = M - 1;
                const float* p = &h[(size_t)grow * 128 + ch * 8];
                rAf[i][0] = *(const float4*)p;
                rAf[i][1] = *(const float4*)(p + 4);
            }
        }
        barrier_raw();                        // As[cur] visible

        f4 acc[2][2];
#pragma unroll
        for (int mi = 0; mi < 2; ++mi)
#pragma unroll
            for (int ni = 0; ni < 2; ++ni) {
                f4 z = {0.f, 0.f, 0.f, 0.f};
                acc[mi][ni] = z;
            }
#pragma unroll
        for (int kc = 0; kc < 4; ++kc) {
            sh8 af[2];
#pragma unroll
            for (int mi = 0; mi < 2; ++mi) {
                const int row = wr * 32 + mi * 16 + lm;
                af[mi] = *(const sh8*)&Asc[row * KD + (((kc * 4 + q) ^ (row & 7)) * 8)];
            }
#pragma unroll
            for (int mi = 0; mi < 2; ++mi)
#pragma unroll
                for (int ni = 0; ni < 2; ++ni)
                    acc[mi][ni] = __builtin_amdgcn_mfma_f32_16x16x32_bf16(
                        wfr[ni][kc], af[mi], acc[mi][ni], 0, 0, 0);
        }

        // ---- packed epilogue: lane owns row (lm), cols col0..col0+3 ----
#pragma unroll
        for (int mi = 0; mi < 2; ++mi) {
            const int row = rowT + wr * 32 + mi * 16 + lm;
            if (row >= M) continue;
#pragma unroll
            for (int ni = 0; ni < 2; ++ni) {
                const int col0 = wc * 32 + ni * 16 + q * 4;
                const f4 a = acc[mi][ni];
                if (wv == 0) {
                    uint2 o;
                    o.x = pkh2(a[0], a[1]);
                    o.y = pkh2(a[2], a[3]);
                    *(uint2*)&Qh[(size_t)row * 128 + col0] = o;
                } else if (wv == 1) {
                    uint2 o;
                    o.x = pkh2(a[0], a[1]);
                    o.y = pkh2(a[2], a[3]);
                    *(uint2*)(KV + (size_t)row * 384 + col0 * 2) = o;
                } else {
                    unsigned ob = 0;
#pragma unroll
                    for (int r = 0; r < 4; ++r) {
                        float tt = rintf(a[r] * VSCALE);
                        tt = fminf(fmaxf(tt, -127.f), 127.f);
                        ob |= ((unsigned)(unsigned char)(int)(tt + 128.f)) << (r * 8);
                    }
                    *(unsigned*)(KV + (size_t)row * 384 + 256 + col0) = ob;
                }
            }
        }
        cur ^= 1;
    }
}

// ========== persistent streaming GEMM, W in regs, PACKED epilogue ==========
// (verified round 11) MFMA operands swapped: lane owns 4 consecutive cols of
// one row -> uint2 stores, float4/uint2 resid reads. Bit-identical numerics.
template<int KD, int RES, int STATS, int RELU>
__global__ __launch_bounds__(512, 4) void gemm3_k(
    const unsigned short* __restrict__ A, const unsigned short* __restrict__ Wt,
    const float* __restrict__ bias, const void* __restrict__ resid,
    unsigned short* __restrict__ C, int M, int ldc, int tiles,
    const float* __restrict__ aff1, float* __restrict__ ostats)
{
    constexpr int CPR = KD / 8;               // 16B chunks per row
    constexpr int NWC = (KD == 128) ? 4 : 8;  // wave-columns
    constexpr int NI  = (KD == 128) ? 2 : 1;  // 16-col fragments per wave
    constexpr int TM  = (KD == 128) ? 64 : 32;// rows per tile
    constexpr int PER = TM * CPR / 512;       // staged chunks per thread
    constexpr int KC  = KD / 32;              // mfma K-steps
    __shared__ __align__(16) unsigned short As[2][TM * KD];
    __shared__ float sacc[256];
    const int tid = threadIdx.x;
    const int wave = tid >> 6, lane = tid & 63;
    const int q = lane >> 4, lm = lane & 15;
    const int wr = wave / NWC, wc = wave % NWC;
    const int colBase = blockIdx.y * 128;
    const unsigned short* Wblk = Wt + (size_t)colBase * KD;

    // ---- prologue A prefetch (issue first) ----
    uint4 rA[PER];
    {
        const int rowT = blockIdx.x * TM;
#pragma unroll
        for (int i = 0; i < PER; ++i) {
            int g = tid + i * 512;
            int row = g / CPR, ch = g % CPR;
            int grow = rowT + row; if (grow >= M) grow = M - 1;
            rA[i] = *(const uint4*)&A[(size_t)grow * KD + ch * 8];
        }
    }

    // ---- W fragments -> registers (once) ----
    sh8 wfr[NI][KC];
#pragma unroll
    for (int ni = 0; ni < NI; ++ni)
#pragma unroll
        for (int kc = 0; kc < KC; ++kc)
            wfr[ni][kc] = *(const sh8*)&Wblk[(size_t)(wc * (16 * NI) + ni * 16 + lm) * KD
                                             + (kc * 4 + q) * 8];
    if (STATS && tid < 256) sacc[tid] = 0.f;

    // ---- per-lane epilogue constants: 4 consecutive cols per ni ----
    float4 bv4[NI], rsc4[NI], rsh4[NI];
#pragma unroll
    for (int ni = 0; ni < NI; ++ni) {
        const int col0 = colBase + wc * (16 * NI) + ni * 16 + q * 4;
        bv4[ni] = *(const float4*)&bias[col0];
        if (RES == 3) {
            rsc4[ni] = *(const float4*)&aff1[col0];
            rsh4[ni] = *(const float4*)&aff1[128 + col0];
        } else {
            rsc4[ni] = make_float4(0.f, 0.f, 0.f, 0.f);
            rsh4[ni] = make_float4(0.f, 0.f, 0.f, 0.f);
        }
    }
    f4 st_s[NI], st_ss[NI];
#pragma unroll
    for (int ni = 0; ni < NI; ++ni) {
        f4 z = {0.f, 0.f, 0.f, 0.f};
        st_s[ni] = z; st_ss[ni] = z;
    }

    int cur = 0;
    for (int t = blockIdx.x; t < tiles; t += gridDim.x) {
        const int rowT = t * TM;
        barrier_raw();                        // As[cur] free
        unsigned short* Asc = As[cur];
#pragma unroll
        for (int i = 0; i < PER; ++i) {       // waits vmcnt via rA register dep
            int g = tid + i * 512;
            int row = g / CPR, ch = g % CPR;
            *(uint4*)&Asc[row * KD + ((ch ^ (row & 7)) * 8)] = rA[i];
        }
        const int tn = t + (int)gridDim.x;
        if (tn < tiles) {                     // issue next prefetch NOW
            const int rowTn = tn * TM;
#pragma unroll
            for (int i = 0; i < PER; ++i) {
                int g = tid + i * 512;
                int row = g / CPR, ch = g % CPR;
                int grow = rowTn + row; if (grow >= M) grow = M - 1;
                rA[i] = *(const uint4*)&A[(size_t)grow * KD + ch * 8];
            }
        }
        barrier_raw();                        // As[cur] visible

        f4 acc[2][NI];
#pragma unroll
        for (int mi = 0; mi < 2; ++mi)
#pragma unroll
            for (int ni = 0; ni < NI; ++ni) {
                f4 z = {0.f, 0.f, 0.f, 0.f};
                acc[mi][ni] = z;
            }
#pragma unroll
        for (int kc = 0; kc < KC; ++kc) {
            sh8 af[2];
#pragma unroll
            for (int mi = 0; mi < 2; ++mi) {
                const int row = wr * 32 + mi * 16 + lm;
                af[mi] = *(const sh8*)&Asc[row * KD + (((kc * 4 + q) ^ (row & 7)) * 8)];
            }
#pragma unroll
            for (int mi = 0; mi < 2; ++mi)
#pragma unroll
                for (int ni = 0; ni < NI; ++ni)
                    acc[mi][ni] = __builtin_amdgcn_mfma_f32_16x16x32_bf16(
                        wfr[ni][kc], af[mi], acc[mi][ni], 0, 0, 0);
        }

        // ---- packed epilogue: lane owns row (lm), cols col0..col0+3 ----
#pragma unroll
        for (int mi = 0; mi < 2; ++mi) {
            const int row = rowT + wr * 32 + mi * 16 + lm;
            if (row >= M) continue;
#pragma unroll
            for (int ni = 0; ni < NI; ++ni) {
                const int col0 = colBase + wc * (16 * NI) + ni * 16 + q * 4;
                const size_t rb = (size_t)row * ldc + col0;
                const f4 a = acc[mi][ni];
                float v0 = a[0] + bv4[ni].x, v1 = a[1] + bv4[ni].y;
                float v2 = a[2] + bv4[ni].z, v3 = a[3] + bv4[ni].w;
                if (RES == 1) {
                    const float4 rv = *(const float4*)&((const float*)resid)[rb];
                    v0 += rv.x; v1 += rv.y; v2 += rv.z; v3 += rv.w;
                }
                if (RES == 3) {
                    const uint2 rv = *(const uint2*)&((const unsigned short*)resid)[rb];
                    v0 += b2f((unsigned short)(rv.x & 0xffff)) * rsc4[ni].x + rsh4[ni].x;
                    v1 += b2f((unsigned short)(rv.x >> 16))    * rsc4[ni].y + rsh4[ni].y;
                    v2 += b2f((unsigned short)(rv.y & 0xffff)) * rsc4[ni].z + rsh4[ni].z;
                    v3 += b2f((unsigned short)(rv.y >> 16))    * rsc4[ni].w + rsh4[ni].w;
                }
                if (RELU) {
                    v0 = fmaxf(v0, 0.f); v1 = fmaxf(v1, 0.f);
                    v2 = fmaxf(v2, 0.f); v3 = fmaxf(v3, 0.f);
                }
                if (STATS) {
                    st_s[ni][0] += v0; st_s[ni][1] += v1;
                    st_s[ni][2] += v2; st_s[ni][3] += v3;
                    st_ss[ni][0] += v0 * v0; st_ss[ni][1] += v1 * v1;
                    st_ss[ni][2] += v2 * v2; st_ss[ni][3] += v3 * v3;
                }
                uint2 o;
                o.x = pk2(v0, v1); o.y = pk2(v2, v3);
                *(uint2*)&C[rb] = o;
            }
        }
        cur ^= 1;
    }

    // ---- stats tail: reduce over lm (shfl 1/2/4/8), lm==0 lanes atomics ----
    if (STATS) {
        barrier_raw();
#pragma unroll
        for (int ni = 0; ni < NI; ++ni) {
#pragma unroll
            for (int m = 1; m <= 8; m <<= 1) {
#pragma unroll
                for (int r = 0; r < 4; ++r) {
                    st_s[ni][r]  += __shfl_xor(st_s[ni][r], m);
                    st_ss[ni][r] += __shfl_xor(st_ss[ni][r], m);
                }
            }
            if (lm == 0) {
                const int col0 = wc * (16 * NI) + ni * 16 + q * 4;
#pragma unroll
                for (int r = 0; r < 4; ++r) {
                    atomicAdd(&sacc[col0 + r], st_s[ni][r]);
                    atomicAdd(&sacc[128 + col0 + r], st_ss[ni][r]);
                }
            }
        }
        barrier_raw();
        if (tid < 128) {
            atomicAdd(&ostats[tid], sacc[tid]);
            atomicAdd(&ostats[128 + tid], sacc[128 + tid]);
        }
    }
}

// ============== BN1 fold into FFN1 weights =================================
__global__ __launch_bounds__(256) void fold_bn1_k(
    const unsigned short* __restrict__ W1t, const float* __restrict__ rstats,
    const float* __restrict__ g1, const float* __restrict__ b1,
    const float* __restrict__ bf1, float invN,
    unsigned short* __restrict__ W1f, float* __restrict__ b1f,
    float* __restrict__ aff1)
{
    __shared__ float sc[128], sh[128];
    const int t = threadIdx.x;
    if (t < 128) {
        const float mu = rstats[t] * invN;
        const float var = rstats[128 + t] * invN - mu * mu;
        const float isg = rsqrtf(var + EPS) * g1[t];
        const float shf = b1[t] - mu * isg;
        sc[t] = isg; sh[t] = shf;
        aff1[t] = isg; aff1[128 + t] = shf;
    }
    __syncthreads();
    float acc = bf1[t];
#pragma unroll
    for (int c = 0; c < 128; c += 8) {
        const uint4 v = *(const uint4*)&W1t[t * 128 + c];
        const float w0 = b2f((unsigned short)(v.x & 0xffff));
        const float w1 = b2f((unsigned short)(v.x >> 16));
        const float w2 = b2f((unsigned short)(v.y & 0xffff));
        const float w3 = b2f((unsigned short)(v.y >> 16));
        const float w4 = b2f((unsigned short)(v.z & 0xffff));
        const float w5 = b2f((unsigned short)(v.z >> 16));
        const float w6 = b2f((unsigned short)(v.w & 0xffff));
        const float w7 = b2f((unsigned short)(v.w >> 16));
        acc += sh[c] * w0 + sh[c + 1] * w1 + sh[c + 2] * w2 + sh[c + 3] * w3
             + sh[c + 4] * w4 + sh[c + 5] * w5 + sh[c + 6] * w6 + sh[c + 7] * w7;
        uint4 o;
        o.x = pk2(w0 * sc[c],     w1 * sc[c + 1]);
        o.y = pk2(w2 * sc[c + 2], w3 * sc[c + 3]);
        o.z = pk2(w4 * sc[c + 4], w5 * sc[c + 5]);
        o.w = pk2(w6 * sc[c + 6], w7 * sc[c + 7]);
        *(uint4*)&W1f[t * 128 + c] = o;
    }
    b1f[t] = acc;
}

// ============== CSR build: two-level LDS counting sort =====================
__global__ __launch_bounds__(256) void bucket_cnt_k(const int* __restrict__ dst,
                                                    int E, int* __restrict__ bCnt)
{
    __shared__ int c[512];
    const int t = threadIdx.x;
    c[t] = 0; c[t + 256] = 0;
    __syncthreads();
    for (int i = blockIdx.x * 256 + t; i < E; i += gridDim.x * 256)
        atomicAdd(&c[dst[i] >> 8], 1);
    __syncthreads();
    if (c[t]) atomicAdd(&bCnt[t], c[t]);
    if (c[t + 256]) atomicAdd(&bCnt[t + 256], c[t + 256]);
}

__global__ __launch_bounds__(512) void bucket_scan_k(const int* __restrict__ bCnt,
                                                     int B, int* __restrict__ bOff,
                                                     int* __restrict__ bCur)
{
    __shared__ int ts[512];
    const int t = threadIdx.x;
    const int v = (t < B) ? bCnt[t] : 0;
    ts[t] = v;
    __syncthreads();
    for (int o = 1; o < 512; o <<= 1) {
        int u = (t >= o) ? ts[t - o] : 0;
        __syncthreads();
        ts[t] += u;
        __syncthreads();
    }
    const int ex = ts[t] - v;
    if (t < B) { bOff[t] = ex; bCur[t] = ex; }
    if (t == B - 1) bOff[B] = ex + v;
}

#define CCH 8192
__global__ __launch_bounds__(512) void coarse_k(const int* __restrict__ src,
                                                const int* __restrict__ dst, int E,
                                                int* __restrict__ bCur,
                                                unsigned* __restrict__ coarse)
{
    __shared__ int cnt[512], off[512], gbase[512], rc[512];
    __shared__ unsigned pk[CCH];
    __shared__ int ga[CCH];
    const int t = threadIdx.x;
    const int e0 = blockIdx.x * CCH;
    const int n = min(CCH, E - e0);
    cnt[t] = 0;
    __syncthreads();
    for (int i = t; i < n; i += 512) atomicAdd(&cnt[dst[e0 + i] >> 8], 1);
    __syncthreads();
    const int v = cnt[t];
    off[t] = v;
    __syncthreads();
    for (int o = 1; o < 512; o <<= 1) {
        int u = (t >= o) ? off[t - o] : 0;
        __syncthreads();
        off[t] += u;
        __syncthreads();
    }
    const int ex = off[t] - v;
    off[t] = ex;
    if (v > 0) gbase[t] = atomicAdd(&bCur[t], v);
    rc[t] = 0;
    __syncthreads();
    for (int i = t; i < n; i += 512) {
        const int d = dst[e0 + i], s = src[e0 + i];
        const int b = d >> 8;
        const int j = atomicAdd(&rc[b], 1);
        const int slot = off[b] + j;
        pk[slot] = ((unsigned)(d & 255) << 17) | (unsigned)s;
        ga[slot] = gbase[b] + j;
    }
    __syncthreads();
    for (int i = t; i < n; i += 512) coarse[ga[i]] = pk[i];
}

__global__ __launch_bounds__(256) void fine_k(const unsigned* __restrict__ coarse,
                                              const int* __restrict__ bOff, int B,
                                              int Nn, int* __restrict__ row_ptr,
                                              int* __restrict__ esrc)
{
    __shared__ int cnt[256], off[256], rc[256];
    const int t = threadIdx.x;
    const int b = blockIdx.x;
    const int base = b << 8;
    const int e0 = bOff[b], e1 = bOff[b + 1];
    cnt[t] = 0;
    __syncthreads();
    for (int i = e0 + t; i < e1; i += 256)
        atomicAdd(&cnt[(coarse[i] >> 17) & 255], 1);
    __syncthreads();
    const int v = cnt[t];
    off[t] = v;
    __syncthreads();
    for (int o = 1; o < 256; o <<= 1) {
        int u = (t >= o) ? off[t - o] : 0;
        __syncthreads();
        off[t] += u;
        __syncthreads();
    }
    const int ex = off[t] - v;
    off[t] = ex;
    rc[t] = 0;
    if (base + t < Nn) row_ptr[base + t] = e0 + ex;
    if (b == B - 1 && t == 0) row_ptr[Nn] = e1;
    __syncthreads();
    for (int i = e0 + t; i < e1; i += 256) {
        const unsigned p = coarse[i];
        const int l = (p >> 17) & 255;
        const int j = atomicAdd(&rc[l], 1);
        esrc[e0 + off[l] + j] = (int)(p & 0x1FFFFu);
    }
}

// ============================ edge attention ===============================
#define EA_ACC(kc, vc, EI) do {                                              \
    float sp = dot2h(u2h((kc).w), q3, dot2h(u2h((kc).z), q2,                 \
               dot2h(u2h((kc).y), q1, dot2h(u2h((kc).x), q0, 0.f))));        \
    sp += __shfl_xor(sp, 1);                                                 \
    float sc = __expf(fminf(fmaxf(sp * 0.25f, -5.f), 5.f));                  \
    sc = ((EI) < nb) ? sc : 0.f;                                             \
    a0 += sc * UB0((vc).x);                                                  \
    a1 += sc * UB1((vc).x);                                                  \
    a2 += sc * UB2((vc).x);                                                  \
    a3 += sc * UB3((vc).x);                                                  \
    a4 += sc * UB0((vc).y);                                                  \
    a5 += sc * UB1((vc).y);                                                  \
    a6 += sc * UB2((vc).y);                                                  \
    a7 += sc * UB3((vc).y);                                                  \
    z += sc;                                                                 \
} while (0)

__global__ __launch_bounds__(256) void edge_attn_k(
    const _Float16* __restrict__ Qh, const unsigned char* __restrict__ KV,
    const int* __restrict__ row_ptr, const int* __restrict__ esrc,
    unsigned short* __restrict__ attnb, int nodeOff, int nodeEnd)
{
    const int wave = threadIdx.x >> 6, lane = threadIdx.x & 63;
    const int node = nodeOff + blockIdx.x * 4 + wave;
    if (node >= nodeEnd) return;
    const int g = lane & 15, p = lane >> 4;
    const uint4 qv = *(const uint4*)&Qh[(size_t)node * 128 + g * 8];
    const h2f q0 = u2h(qv.x), q1 = u2h(qv.y), q2 = u2h(qv.z), q3 = u2h(qv.w);
    const int e0 = row_ptr[node], e1 = row_ptr[node + 1];
    const int cnt = e1 - e0;
    const int e1m1 = e1 - 1;
    float a0 = 0.f, a1 = 0.f, a2 = 0.f, a3 = 0.f;
    float a4 = 0.f, a5 = 0.f, a6 = 0.f, a7 = 0.f, z = 0.f;
    for (int base = 0; base < cnt; base += 64) {
        const int nb = min(cnt - base, 64);
        const int eb = e0 + base + p;
        {
            const int s0 = esrc[min(eb, e1m1)];
            const unsigned char* r = KV + (size_t)((unsigned)s0 * 384u);
            const int s1 = esrc[min(eb + 4, e1m1)];
            const unsigned char* rB = KV + (size_t)((unsigned)s1 * 384u);
            uint4 kvA = *(const uint4*)(r + g * 16);
            uint2 vvA = *(const uint2*)(r + 256 + g * 8);
            uint4 kvB = *(const uint4*)(rB + g * 16);
            uint2 vvB = *(const uint2*)(rB + 256 + g * 8);
            for (int j = 0; j < nb; j += 8) {
                {   // group A: edges j..j+3
                    const uint4 kc = kvA; const uint2 vc = vvA;
                    if (j + 8 < nb) {                    // wave-uniform
                        const int sn = esrc[min(eb + j + 8, e1m1)];
                        const unsigned char* rn = KV + (size_t)((unsigned)sn * 384u);
                        kvA = *(const uint4*)(rn + g * 16);
                        vvA = *(const uint2*)(rn + 256 + g * 8);
                    }
                    EA_ACC(kc, vc, j + p);
                }
                {   // group B: edges j+4..j+7 (masked if beyond nb)
                    const uint4 kc = kvB; const uint2 vc = vvB;
                    if (j + 12 < nb) {                   // wave-uniform
                        const int sn = esrc[min(eb + j + 12, e1m1)];
                        const unsigned char* rn = KV + (size_t)((unsigned)sn * 384u);
                        kvB = *(const uint4*)(rn + g * 16);
                        vvB = *(const uint2*)(rn + 256 + g * 8);
                    }
                    EA_ACC(kc, vc, j + 4 + p);
                }
            }
        }
    }
    a0 += __shfl_xor(a0, 16); a0 += __shfl_xor(a0, 32);
    a1 += __shfl_xor(a1, 16); a1 += __shfl_xor(a1, 32);
    a2 += __shfl_xor(a2, 16); a2 += __shfl_xor(a2, 32);
    a3 += __shfl_xor(a3, 16); a3 += __shfl_xor(a3, 32);
    a4 += __shfl_xor(a4, 16); a4 += __shfl_xor(a4, 32);
    a5 += __shfl_xor(a5, 16); a5 += __shfl_xor(a5, 32);
    a6 += __shfl_xor(a6, 16); a6 += __shfl_xor(a6, 32);
    a7 += __shfl_xor(a7, 16); a7 += __shfl_xor(a7, 32);
    z  += __shfl_xor(z, 16);  z  += __shfl_xor(z, 32);
    const float inv = 1.f / (z * VSCALE);
    const float c = 128.f * z;
    if (p == 0) {
        uint4 o;
        o.x = pk2((a0 - c) * inv, (a1 - c) * inv);
        o.y = pk2((a2 - c) * inv, (a3 - c) * inv);
        o.z = pk2((a4 - c) * inv, (a5 - c) * inv);
        o.w = pk2((a6 - c) * inv, (a7 - c) * inv);
        *(uint4*)&attnb[(size_t)node * 128 + g * 8] = o;
    }
}

// ============================ BN apply (folds finalize) ====================
__global__ __launch_bounds__(256) void bn_apply_b_k(const unsigned short* __restrict__ X,
                                                    const float* __restrict__ rstats,
                                                    const float* __restrict__ gma,
                                                    const float* __restrict__ bta,
                                                    float invN, int total8,
                                                    float* __restrict__ out)
{
    __shared__ float aff[256];
    if (threadIdx.x < 128) {
        const int c = threadIdx.x;
        const float mu = rstats[c] * invN;
        const float var = rstats[128 + c] * invN - mu * mu;
        const float isg = rsqrtf(var + EPS) * gma[c];
        aff[c] = isg;
        aff[128 + c] = bta[c] - mu * isg;
    }
    __syncthreads();
    for (int i = blockIdx.x * blockDim.x + threadIdx.x; i < total8;
         i += gridDim.x * blockDim.x) {
        const int c8 = (i & 15) * 8;
        const float4 sc0 = *(const float4*)&aff[c8];
        const float4 sc1 = *(const float4*)&aff[c8 + 4];
        const float4 sh0 = *(const float4*)&aff[128 + c8];
        const float4 sh1 = *(const float4*)&aff[128 + c8 + 4];
        const uint4 v = ((const uint4*)X)[i];
        float4 o0, o1;
        o0.x = b2f((unsigned short)(v.x & 0xffff)) * sc0.x + sh0.x;
        o0.y = b2f((unsigned short)(v.x >> 16))    * sc0.y + sh0.y;
        o0.z = b2f((unsigned short)(v.y & 0xffff)) * sc0.z + sh0.z;
        o0.w = b2f((unsigned short)(v.y >> 16))    * sc0.w + sh0.w;
        o1.x = b2f((unsigned short)(v.z & 0xffff)) * sc1.x + sh1.x;
        o1.y = b2f((unsigned short)(v.z >> 16))    * sc1.y + sh1.y;
        o1.z = b2f((unsigned short)(v.w & 0xffff)) * sc1.z + sh1.z;
        o1.w = b2f((unsigned short)(v.w >> 16))    * sc1.w + sh1.w;
        ((float4*)out)[i * 2]     = o0;
        ((float4*)out)[i * 2 + 1] = o1;
    }
}

// ============================ launch =======================================
extern "C" void kernel_launch(void* const* d_in, const int* in_sizes, int n_in,
                              void* d_out, int out_size, void* d_ws, size_t ws_size,
                              hipStream_t stream)
{
    const float* h   = (const float*)d_in[0];
    const float* Wq  = (const float*)d_in[1];
    const float* Wk  = (const float*)d_in[2];
    const float* Wv  = (const float*)d_in[3];
    const float* Wo  = (const float*)d_in[4];
    const float* bo  = (const float*)d_in[5];
    const float* g1  = (const float*)d_in[6];
    const float* b1  = (const float*)d_in[7];
    const float* Wf1 = (const float*)d_in[8];
    const float* bf1 = (const float*)d_in[9];
    const float* Wf2 = (const float*)d_in[10];
    const float* bf2 = (const float*)d_in[11];
    const float* g2  = (const float*)d_in[12];
    const float* b2  = (const float*)d_in[13];
    const int*   src = (const int*)d_in[14];
    const int*   dstv= (const int*)d_in[15];
    const int N = in_sizes[0] / 128;
    const int E = in_sizes[14];
    const int B = (N + 255) >> 8;
    const float invN = 1.f / (float)N;

    // ---- workspace layout ----
    unsigned short* Wt = (unsigned short*)d_ws;               // 131072 bf16
    float* stats1 = (float*)((char*)d_ws + 262144);           // 256
    float* stats2 = stats1 + 256;                             // 256
    int* bCnt = (int*)(stats2 + 256);                         // 512
    int* bOff = bCnt + 512;                                   // 513
    int* bCur = bOff + 513;                                   // 512
    uintptr_t big = ((uintptr_t)(bCur + 512) + 255) & ~(uintptr_t)255;
    _Float16* Qh = (_Float16*)big;                            // N*128 f16  (N*256B)
    unsigned char* KV = (unsigned char*)(Qh + (size_t)N * 128);   // N*384B packed K|V
    uintptr_t a2 = ((uintptr_t)(KV + (size_t)N * 384) + 255) & ~(uintptr_t)255;
    unsigned short* attnb = (unsigned short*)a2;              // N*128 bf16
    unsigned short* xb = attnb + (size_t)N * 128;             // N*128 bf16
    int* row_ptr = (int*)(xb + (size_t)N * 128);              // N+1
    // overlays (lifetimes disjoint):
    unsigned* coarse = (unsigned*)attnb;   // CSR temp; attnb born at edge_attn
    int* esrc = (int*)xb;                  // CSR out; xb born at Wo-GEMM
    unsigned short* hidden = (unsigned short*)Qh;  // N*256 bf16 (N*512B over Qh+KV head)
    unsigned short* yb = attnb;            // FFN2 bf16 out; attnb dead after Wo-GEMM
    // fold outputs: past hidden end, inside Qh+KV region (KV dead after edge_attn)
    uintptr_t fb = (big + (size_t)N * 512 + 255) & ~(uintptr_t)255;
    float* aff1 = (float*)fb;                          // 256 f
    float* b1f  = aff1 + 256;                          // 256 f
    unsigned short* W1f = (unsigned short*)(b1f + 256);// 256*128 bf16 (64KB)

    unsigned short* Wf1T = Wt + 65536;
    unsigned short* Wf2T = Wt + 98304;

    float* out = (float*)d_out;
    const dim3 b256(256);
    const dim3 b512(512);
    const int tiles64 = (N + 63) / 64;
    const int tiles32 = (N + 31) / 32;

    hipMemsetAsync(stats1, 0, 4096, stream);

    // ---- weight prep ----
    prep_all_k<<<dim3(512), b256, 0, stream>>>(Wq, Wk, Wv, Wo, Wf1, Wf2, Wt);

    // ---- CSR build ----
    bucket_cnt_k<<<dim3(256), b256, 0, stream>>>(dstv, E, bCnt);
    bucket_scan_k<<<dim3(1), dim3(512), 0, stream>>>(bCnt, B, bOff, bCur);
    coarse_k<<<dim3((E + CCH - 1) / CCH), dim3(512), 0, stream>>>(src, dstv, E, bCur, coarse);
    fine_k<<<dim3(B), b256, 0, stream>>>(coarse, bOff, B, N, row_ptr, esrc);

    // ---- fused QKV (persistent gemm, W in regs, packed epilogue) ----
    qkv3_k<<<dim3(341, 3), b512, 0, stream>>>(h, Wt, Qh, KV, N, tiles64);

    // ---- sparse attention -> attnb bf16 (single launch) ----
    edge_attn_k<<<dim3((N + 3) / 4), b256, 0, stream>>>(
        Qh, KV, row_ptr, esrc, attnb, 0, N);

    // ---- x = h + attn @ Wo + bo (bf16 out) ; BN1 raw moments ----
    gemm3_k<128, 1, 1, 0><<<dim3(512, 1), b512, 0, stream>>>(
        attnb, Wt + 49152, bo, h, xb, N, 128, tiles64, nullptr, stats1);

    // ---- fold BN1 into FFN1 weights; emit aff1 for FFN2 resid ----
    fold_bn1_k<<<dim3(1), b256, 0, stream>>>(Wf1T, stats1, g1, b1, bf1, invN,
                                             W1f, b1f, aff1);

    // ---- FFN1: plain GEMM on raw x with folded weights, relu ----
    gemm3_k<128, 0, 0, 1><<<dim3(512, 2), b512, 0, stream>>>(
        xb, W1f, b1f, nullptr, hidden, N, 256, tiles64, nullptr, nullptr);

    // ---- FFN2: resid = BN1(x) via aff1; BN2 raw moments -> yb bf16 ----
    gemm3_k<256, 3, 1, 0><<<dim3(512, 1), b512, 0, stream>>>(
        hidden, Wf2T, bf2, xb, yb, N, 128, tiles32, aff1, stats2);

    // ---- BN2 apply (finalize folded): yb bf16 -> out fp32 ----
    bn_apply_b_k<<<dim3(1024), b256, 0, stream>>>(yb, stats2, g2, b2, invN, N * 16, out);
}

// Round 13
// 419.050 us; speedup vs baseline: 1.1256x; 1.0485x over previous
//
#include <hip/hip_runtime.h>

#define EPS 1e-5f
#define VSCALE 20.0f

typedef __attribute__((ext_vector_type(8))) short sh8;
typedef __attribute__((ext_vector_type(4))) float f4;
typedef __attribute__((ext_vector_type(2))) _Float16 h2f;

static __device__ __forceinline__ unsigned short f2b(float f) {
    union { float f; unsigned u; } v; v.f = f;
    unsigned r = v.u + 0x7FFF + ((v.u >> 16) & 1);  // RNE
    return (unsigned short)(r >> 16);
}
static __device__ __forceinline__ float b2f(unsigned short b) {
    union { unsigned u; float f; } v; v.u = ((unsigned)b) << 16; return v.f;
}
static __device__ __forceinline__ unsigned pk2(float a, float b) {
    return (unsigned)f2b(a) | ((unsigned)f2b(b) << 16);
}
static __device__ __forceinline__ h2f u2h(unsigned u) {
    union { unsigned u; h2f h; } c; c.u = u; return c.h;
}
static __device__ __forceinline__ unsigned pkh2(float a, float b) {
    union { h2f h; unsigned u; } c;
    c.h.x = (_Float16)a; c.h.y = (_Float16)b;
    return c.u;
}
static __device__ __forceinline__ float dot2h(h2f a, h2f b, float c) {
#if __has_builtin(__builtin_amdgcn_fdot2)
    return __builtin_amdgcn_fdot2(a, b, c, false);
#else
    return (float)a.x * (float)b.x + (float)a.y * (float)b.y + c;
#endif
}
// u8 lane extracts as float (v_cvt_f32_ubyteN when available)
#if __has_builtin(__builtin_amdgcn_cvt_f32_ubyte0)
#define UB0(x) __builtin_amdgcn_cvt_f32_ubyte0(x)
#define UB1(x) __builtin_amdgcn_cvt_f32_ubyte1(x)
#define UB2(x) __builtin_amdgcn_cvt_f32_ubyte2(x)
#define UB3(x) __builtin_amdgcn_cvt_f32_ubyte3(x)
#else
#define UB0(x) ((float)((x) & 0xffu))
#define UB1(x) ((float)(((x) >> 8) & 0xffu))
#define UB2(x) ((float)(((x) >> 16) & 0xffu))
#define UB3(x) ((float)((x) >> 24))
#endif

// raw barrier: lgkmcnt-only (never drains vmcnt -> prefetch stays in flight)
static __device__ __forceinline__ void barrier_raw() {
    __builtin_amdgcn_sched_barrier(0);
    asm volatile("s_waitcnt lgkmcnt(0)" ::: "memory");
    __builtin_amdgcn_s_barrier();
    __builtin_amdgcn_sched_barrier(0);
}

// ===================== weight prep (all 6, one launch) =====================
__global__ __launch_bounds__(256) void prep_all_k(
    const float* __restrict__ Wq, const float* __restrict__ Wk,
    const float* __restrict__ Wv, const float* __restrict__ Wo,
    const float* __restrict__ Wf1, const float* __restrict__ Wf2,
    unsigned short* __restrict__ Wt)
{
    int i = blockIdx.x * 256 + threadIdx.x;      // 0..131071
    if (i < 65536) {
        int s = i >> 14;
        const float* W = (s == 0) ? Wq : (s == 1) ? Wk : (s == 2) ? Wv : Wo;
        int l = i & 16383, k = l >> 7, n = l & 127;
        Wt[(i & ~16383) + n * 128 + k] = f2b(W[l]);
    } else if (i < 98304) {
        int l = i - 65536, k = l >> 8, n = l & 255;
        Wt[65536 + n * 128 + k] = f2b(Wf1[l]);
    } else {
        int l = i - 98304, k = l >> 7, n = l & 127;
        Wt[98304 + n * 256 + k] = f2b(Wf2[l]);
    }
}

// ===================== QKV: single-pass, W in regs, packed epilogue ========
// h read ONCE. 8 waves x 48 cols = 384 output cols (Q|K|V concat: Wt's
// per-product [128][128] blocks are contiguous -> one [384][128] matrix).
// 32-row tiles. Per-output MFMA kc-chain identical to prior version.
__global__ __launch_bounds__(512, 4) void qkv3_k(
    const float* __restrict__ h, const unsigned short* __restrict__ Wt,
    _Float16* __restrict__ Qh, unsigned char* __restrict__ KV,
    int M, int tiles)
{
    constexpr int KD = 128;
    __shared__ __align__(16) unsigned short As[2][32 * KD];
    const int tid = threadIdx.x;
    const int wave = tid >> 6, lane = tid & 63;
    const int q = lane >> 4, lm = lane & 15;
    const int wc = wave;                         // 8 wave-cols x 48 cols

    // ---- prologue A prefetch (fp32, 8 floats/thread) ----
    float4 rAf[2];
    {
        const int rowT = blockIdx.x * 32;
        int row = tid >> 4, ch = tid & 15;
        int grow = rowT + row; if (grow >= M) grow = M - 1;
        const float* p = &h[(size_t)grow * 128 + ch * 8];
        rAf[0] = *(const float4*)p;
        rAf[1] = *(const float4*)(p + 4);
    }

    // ---- W fragments -> registers (once): 3 x 16-col groups per wave ----
    sh8 wfr[3][4];
#pragma unroll
    for (int ni = 0; ni < 3; ++ni)
#pragma unroll
        for (int kc = 0; kc < 4; ++kc)
            wfr[ni][kc] = *(const sh8*)&Wt[(size_t)(wc * 48 + ni * 16 + lm) * KD
                                           + (kc * 4 + q) * 8];

    int cur = 0;
    for (int t = blockIdx.x; t < tiles; t += gridDim.x) {
        const int rowT = t * 32;
        barrier_raw();                        // As[cur] free
        unsigned short* Asc = As[cur];
        {
            int row = tid >> 4, ch = tid & 15;
            uint4 v;
            v.x = pk2(rAf[0].x, rAf[0].y);
            v.y = pk2(rAf[0].z, rAf[0].w);
            v.z = pk2(rAf[1].x, rAf[1].y);
            v.w = pk2(rAf[1].z, rAf[1].w);
            *(uint4*)&Asc[row * KD + ((ch ^ (row & 7)) * 8)] = v;
        }
        const int tn = t + (int)gridDim.x;
        if (tn < tiles) {                     // issue next prefetch NOW
            const int rowTn = tn * 32;
            int row = tid >> 4, ch = tid & 15;
            int grow = rowTn + row; if (grow >= M) grow = M - 1;
            const float* p = &h[(size_t)grow * 128 + ch * 8];
            rAf[0] = *(const float4*)p;
            rAf[1] = *(const float4*)(p + 4);
        }
        barrier_raw();                        // As[cur] visible

        f4 acc[2][3];
#pragma unroll
        for (int mi = 0; mi < 2; ++mi)
#pragma unroll
            for (int ni = 0; ni < 3; ++ni) {
                f4 z = {0.f, 0.f, 0.f, 0.f};
                acc[mi][ni] = z;
            }
#pragma unroll
        for (int kc = 0; kc < 4; ++kc) {
            sh8 af[2];
#pragma unroll
            for (int mi = 0; mi < 2; ++mi) {
                const int row = mi * 16 + lm;
                af[mi] = *(const sh8*)&Asc[row * KD + (((kc * 4 + q) ^ (row & 7)) * 8)];
            }
#pragma unroll
            for (int mi = 0; mi < 2; ++mi)
#pragma unroll
                for (int ni = 0; ni < 3; ++ni)
                    acc[mi][ni] = __builtin_amdgcn_mfma_f32_16x16x32_bf16(
                        wfr[ni][kc], af[mi], acc[mi][ni], 0, 0, 0);
        }

        // ---- packed epilogue: lane owns row (lm), 4 consecutive cols ----
#pragma unroll
        for (int mi = 0; mi < 2; ++mi) {
            const int row = rowT + mi * 16 + lm;
            if (row >= M) continue;
#pragma unroll
            for (int ni = 0; ni < 3; ++ni) {
                const int colg = wc * 48 + ni * 16 + q * 4;   // 0..383
                const int prod = colg >> 7;                   // wave-uniform per ni
                const int lc = colg & 127;
                const f4 a = acc[mi][ni];
                if (prod == 0) {
                    uint2 o;
                    o.x = pkh2(a[0], a[1]);
                    o.y = pkh2(a[2], a[3]);
                    *(uint2*)&Qh[(size_t)row * 128 + lc] = o;
                } else if (prod == 1) {
                    uint2 o;
                    o.x = pkh2(a[0], a[1]);
                    o.y = pkh2(a[2], a[3]);
                    *(uint2*)(KV + (size_t)row * 384 + lc * 2) = o;
                } else {
                    unsigned ob = 0;
#pragma unroll
                    for (int r = 0; r < 4; ++r) {
                        float tt = rintf(a[r] * VSCALE);
                        tt = fminf(fmaxf(tt, -127.f), 127.f);
                        ob |= ((unsigned)(unsigned char)(int)(tt + 128.f)) << (r * 8);
                    }
                    *(unsigned*)(KV + (size_t)row * 384 + 256 + lc) = ob;
                }
            }
        }
        cur ^= 1;
    }
}

// ========== persistent streaming GEMM, W in regs, PACKED epilogue ==========
// NCOL template param sets wave->column fan-out (single-pass over A):
//  <128,128>: NWC=4, TM=64 (Wo — identical to verified round-12 geometry)
//  <128,256>: NWC=8, TM=32 (FFN1 single-pass, all 256 cols)
//  <256,128>: NWC=8, TM=32 (FFN2)
template<int KD, int NCOL, int RES, int STATS, int RELU>
__global__ __launch_bounds__(512, 4) void gemm3_k(
    const unsigned short* __restrict__ A, const unsigned short* __restrict__ Wt,
    const float* __restrict__ bias, const void* __restrict__ resid,
    unsigned short* __restrict__ C, int M, int ldc, int tiles,
    const float* __restrict__ aff1, float* __restrict__ ostats)
{
    constexpr int CPR = KD / 8;               // 16B chunks per row
    constexpr int NI  = (KD == 128) ? 2 : 1;  // 16-col fragments per wave
    constexpr int NWC = NCOL / (16 * NI);     // wave-columns
    constexpr int TM  = 256 / NWC;            // rows per tile
    constexpr int PER = TM * CPR / 512;       // staged chunks per thread
    constexpr int KC  = KD / 32;              // mfma K-steps
    __shared__ __align__(16) unsigned short As[2][TM * KD];
    __shared__ float sacc[256];
    const int tid = threadIdx.x;
    const int wave = tid >> 6, lane = tid & 63;
    const int q = lane >> 4, lm = lane & 15;
    const int wr = wave / NWC, wc = wave % NWC;
    const int colBase = blockIdx.y * NCOL;
    const unsigned short* Wblk = Wt + (size_t)colBase * KD;

    // ---- prologue A prefetch (issue first) ----
    uint4 rA[PER];
    {
        const int rowT = blockIdx.x * TM;
#pragma unroll
        for (int i = 0; i < PER; ++i) {
            int g = tid + i * 512;
            int row = g / CPR, ch = g % CPR;
            int grow = rowT + row; if (grow >= M) grow = M - 1;
            rA[i] = *(const uint4*)&A[(size_t)grow * KD + ch * 8];
        }
    }

    // ---- W fragments -> registers (once) ----
    sh8 wfr[NI][KC];
#pragma unroll
    for (int ni = 0; ni < NI; ++ni)
#pragma unroll
        for (int kc = 0; kc < KC; ++kc)
            wfr[ni][kc] = *(const sh8*)&Wblk[(size_t)(wc * (16 * NI) + ni * 16 + lm) * KD
                                             + (kc * 4 + q) * 8];
    if (STATS && tid < 256) sacc[tid] = 0.f;

    // ---- per-lane epilogue constants: 4 consecutive cols per ni ----
    float4 bv4[NI], rsc4[NI], rsh4[NI];
#pragma unroll
    for (int ni = 0; ni < NI; ++ni) {
        const int col0 = colBase + wc * (16 * NI) + ni * 16 + q * 4;
        bv4[ni] = *(const float4*)&bias[col0];
        if (RES == 3) {
            rsc4[ni] = *(const float4*)&aff1[col0];
            rsh4[ni] = *(const float4*)&aff1[128 + col0];
        } else {
            rsc4[ni] = make_float4(0.f, 0.f, 0.f, 0.f);
            rsh4[ni] = make_float4(0.f, 0.f, 0.f, 0.f);
        }
    }
    f4 st_s[NI], st_ss[NI];
#pragma unroll
    for (int ni = 0; ni < NI; ++ni) {
        f4 z = {0.f, 0.f, 0.f, 0.f};
        st_s[ni] = z; st_ss[ni] = z;
    }

    int cur = 0;
    for (int t = blockIdx.x; t < tiles; t += gridDim.x) {
        const int rowT = t * TM;
        barrier_raw();                        // As[cur] free
        unsigned short* Asc = As[cur];
#pragma unroll
        for (int i = 0; i < PER; ++i) {       // waits vmcnt via rA register dep
            int g = tid + i * 512;
            int row = g / CPR, ch = g % CPR;
            *(uint4*)&Asc[row * KD + ((ch ^ (row & 7)) * 8)] = rA[i];
        }
        const int tn = t + (int)gridDim.x;
        if (tn < tiles) {                     // issue next prefetch NOW
            const int rowTn = tn * TM;
#pragma unroll
            for (int i = 0; i < PER; ++i) {
                int g = tid + i * 512;
                int row = g / CPR, ch = g % CPR;
                int grow = rowTn + row; if (grow >= M) grow = M - 1;
                rA[i] = *(const uint4*)&A[(size_t)grow * KD + ch * 8];
            }
        }
        barrier_raw();                        // As[cur] visible

        f4 acc[2][NI];
#pragma unroll
        for (int mi = 0; mi < 2; ++mi)
#pragma unroll
            for (int ni = 0; ni < NI; ++ni) {
                f4 z = {0.f, 0.f, 0.f, 0.f};
                acc[mi][ni] = z;
            }
#pragma unroll
        for (int kc = 0; kc < KC; ++kc) {
            sh8 af[2];
#pragma unroll
            for (int mi = 0; mi < 2; ++mi) {
                const int row = wr * 32 + mi * 16 + lm;
                af[mi] = *(const sh8*)&Asc[row * KD + (((kc * 4 + q) ^ (row & 7)) * 8)];
            }
#pragma unroll
            for (int mi = 0; mi < 2; ++mi)
#pragma unroll
                for (int ni = 0; ni < NI; ++ni)
                    acc[mi][ni] = __builtin_amdgcn_mfma_f32_16x16x32_bf16(
                        wfr[ni][kc], af[mi], acc[mi][ni], 0, 0, 0);
        }

        // ---- packed epilogue: lane owns row (lm), cols col0..col0+3 ----
#pragma unroll
        for (int mi = 0; mi < 2; ++mi) {
            const int row = rowT + wr * 32 + mi * 16 + lm;
            if (row >= M) continue;
#pragma unroll
            for (int ni = 0; ni < NI; ++ni) {
                const int col0 = colBase + wc * (16 * NI) + ni * 16 + q * 4;
                const size_t rb = (size_t)row * ldc + col0;
                const f4 a = acc[mi][ni];
                float v0 = a[0] + bv4[ni].x, v1 = a[1] + bv4[ni].y;
                float v2 = a[2] + bv4[ni].z, v3 = a[3] + bv4[ni].w;
                if (RES == 1) {
                    const float4 rv = *(const float4*)&((const float*)resid)[rb];
                    v0 += rv.x; v1 += rv.y; v2 += rv.z; v3 += rv.w;
                }
                if (RES == 3) {
                    const uint2 rv = *(const uint2*)&((const unsigned short*)resid)[rb];
                    v0 += b2f((unsigned short)(rv.x & 0xffff)) * rsc4[ni].x + rsh4[ni].x;
                    v1 += b2f((unsigned short)(rv.x >> 16))    * rsc4[ni].y + rsh4[ni].y;
                    v2 += b2f((unsigned short)(rv.y & 0xffff)) * rsc4[ni].z + rsh4[ni].z;
                    v3 += b2f((unsigned short)(rv.y >> 16))    * rsc4[ni].w + rsh4[ni].w;
                }
                if (RELU) {
                    v0 = fmaxf(v0, 0.f); v1 = fmaxf(v1, 0.f);
                    v2 = fmaxf(v2, 0.f); v3 = fmaxf(v3, 0.f);
                }
                if (STATS) {
                    st_s[ni][0] += v0; st_s[ni][1] += v1;
                    st_s[ni][2] += v2; st_s[ni][3] += v3;
                    st_ss[ni][0] += v0 * v0; st_ss[ni][1] += v1 * v1;
                    st_ss[ni][2] += v2 * v2; st_ss[ni][3] += v3 * v3;
                }
                uint2 o;
                o.x = pk2(v0, v1); o.y = pk2(v2, v3);
                *(uint2*)&C[rb] = o;
            }
        }
        cur ^= 1;
    }

    // ---- stats tail: reduce over lm (shfl 1/2/4/8), lm==0 lanes atomics ----
    if (STATS) {
        barrier_raw();
#pragma unroll
        for (int ni = 0; ni < NI; ++ni) {
#pragma unroll
            for (int m = 1; m <= 8; m <<= 1) {
#pragma unroll
                for (int r = 0; r < 4; ++r) {
                    st_s[ni][r]  += __shfl_xor(st_s[ni][r], m);
                    st_ss[ni][r] += __shfl_xor(st_ss[ni][r], m);
                }
            }
            if (lm == 0) {
                const int col0 = wc * (16 * NI) + ni * 16 + q * 4;
#pragma unroll
                for (int r = 0; r < 4; ++r) {
                    atomicAdd(&sacc[col0 + r], st_s[ni][r]);
                    atomicAdd(&sacc[128 + col0 + r], st_ss[ni][r]);
                }
            }
        }
        barrier_raw();
        if (tid < 128) {
            atomicAdd(&ostats[tid], sacc[tid]);
            atomicAdd(&ostats[128 + tid], sacc[128 + tid]);
        }
    }
}

// ============== BN1 fold into FFN1 weights =================================
__global__ __launch_bounds__(256) void fold_bn1_k(
    const unsigned short* __restrict__ W1t, const float* __restrict__ rstats,
    const float* __restrict__ g1, const float* __restrict__ b1,
    const float* __restrict__ bf1, float invN,
    unsigned short* __restrict__ W1f, float* __restrict__ b1f,
    float* __restrict__ aff1)
{
    __shared__ float sc[128], sh[128];
    const int t = threadIdx.x;
    if (t < 128) {
        const float mu = rstats[t] * invN;
        const float var = rstats[128 + t] * invN - mu * mu;
        const float isg = rsqrtf(var + EPS) * g1[t];
        const float shf = b1[t] - mu * isg;
        sc[t] = isg; sh[t] = shf;
        aff1[t] = isg; aff1[128 + t] = shf;
    }
    __syncthreads();
    float acc = bf1[t];
#pragma unroll
    for (int c = 0; c < 128; c += 8) {
        const uint4 v = *(const uint4*)&W1t[t * 128 + c];
        const float w0 = b2f((unsigned short)(v.x & 0xffff));
        const float w1 = b2f((unsigned short)(v.x >> 16));
        const float w2 = b2f((unsigned short)(v.y & 0xffff));
        const float w3 = b2f((unsigned short)(v.y >> 16));
        const float w4 = b2f((unsigned short)(v.z & 0xffff));
        const float w5 = b2f((unsigned short)(v.z >> 16));
        const float w6 = b2f((unsigned short)(v.w & 0xffff));
        const float w7 = b2f((unsigned short)(v.w >> 16));
        acc += sh[c] * w0 + sh[c + 1] * w1 + sh[c + 2] * w2 + sh[c + 3] * w3
             + sh[c + 4] * w4 + sh[c + 5] * w5 + sh[c + 6] * w6 + sh[c + 7] * w7;
        uint4 o;
        o.x = pk2(w0 * sc[c],     w1 * sc[c + 1]);
        o.y = pk2(w2 * sc[c + 2], w3 * sc[c + 3]);
        o.z = pk2(w4 * sc[c + 4], w5 * sc[c + 5]);
        o.w = pk2(w6 * sc[c + 6], w7 * sc[c + 7]);
        *(uint4*)&W1f[t * 128 + c] = o;
    }
    b1f[t] = acc;
}

// ============== CSR build: two-level LDS counting sort =====================
__global__ __launch_bounds__(256) void bucket_cnt_k(const int* __restrict__ dst,
                                                    int E, int* __restrict__ bCnt)
{
    __shared__ int c[512];
    const int t = threadIdx.x;
    c[t] = 0; c[t + 256] = 0;
    __syncthreads();
    for (int i = blockIdx.x * 256 + t; i < E; i += gridDim.x * 256)
        atomicAdd(&c[dst[i] >> 8], 1);
    __syncthreads();
    if (c[t]) atomicAdd(&bCnt[t], c[t]);
    if (c[t + 256]) atomicAdd(&bCnt[t + 256], c[t + 256]);
}

__global__ __launch_bounds__(512) void bucket_scan_k(const int* __restrict__ bCnt,
                                                     int B, int* __restrict__ bOff,
                                                     int* __restrict__ bCur)
{
    __shared__ int ts[512];
    const int t = threadIdx.x;
    const int v = (t < B) ? bCnt[t] : 0;
    ts[t] = v;
    __syncthreads();
    for (int o = 1; o < 512; o <<= 1) {
        int u = (t >= o) ? ts[t - o] : 0;
        __syncthreads();
        ts[t] += u;
        __syncthreads();
    }
    const int ex = ts[t] - v;
    if (t < B) { bOff[t] = ex; bCur[t] = ex; }
    if (t == B - 1) bOff[B] = ex + v;
}

#define CCH 8192
__global__ __launch_bounds__(512) void coarse_k(const int* __restrict__ src,
                                                const int* __restrict__ dst, int E,
                                                int* __restrict__ bCur,
                                                unsigned* __restrict__ coarse)
{
    __shared__ int cnt[512], off[512], gbase[512], rc[512];
    __shared__ unsigned pk[CCH];
    __shared__ int ga[CCH];
    const int t = threadIdx.x;
    const int e0 = blockIdx.x * CCH;
    const int n = min(CCH, E - e0);
    cnt[t] = 0;
    __syncthreads();
    for (int i = t; i < n; i += 512) atomicAdd(&cnt[dst[e0 + i] >> 8], 1);
    __syncthreads();
    const int v = cnt[t];
    off[t] = v;
    __syncthreads();
    for (int o = 1; o < 512; o <<= 1) {
        int u = (t >= o) ? off[t - o] : 0;
        __syncthreads();
        off[t] += u;
        __syncthreads();
    }
    const int ex = off[t] - v;
    off[t] = ex;
    if (v > 0) gbase[t] = atomicAdd(&bCur[t], v);
    rc[t] = 0;
    __syncthreads();
    for (int i = t; i < n; i += 512) {
        const int d = dst[e0 + i], s = src[e0 + i];
        const int b = d >> 8;
        const int j = atomicAdd(&rc[b], 1);
        const int slot = off[b] + j;
        pk[slot] = ((unsigned)(d & 255) << 17) | (unsigned)s;
        ga[slot] = gbase[b] + j;
    }
    __syncthreads();
    for (int i = t; i < n; i += 512) coarse[ga[i]] = pk[i];
}

__global__ __launch_bounds__(256) void fine_k(const unsigned* __restrict__ coarse,
                                              const int* __restrict__ bOff, int B,
                                              int Nn, int* __restrict__ row_ptr,
                                              int* __restrict__ esrc)
{
    __shared__ int cnt[256], off[256], rc[256];
    const int t = threadIdx.x;
    const int b = blockIdx.x;
    const int base = b << 8;
    const int e0 = bOff[b], e1 = bOff[b + 1];
    cnt[t] = 0;
    __syncthreads();
    for (int i = e0 + t; i < e1; i += 256)
        atomicAdd(&cnt[(coarse[i] >> 17) & 255], 1);
    __syncthreads();
    const int v = cnt[t];
    off[t] = v;
    __syncthreads();
    for (int o = 1; o < 256; o <<= 1) {
        int u = (t >= o) ? off[t - o] : 0;
        __syncthreads();
        off[t] += u;
        __syncthreads();
    }
    const int ex = off[t] - v;
    off[t] = ex;
    rc[t] = 0;
    if (base + t < Nn) row_ptr[base + t] = e0 + ex;
    if (b == B - 1 && t == 0) row_ptr[Nn] = e1;
    __syncthreads();
    for (int i = e0 + t; i < e1; i += 256) {
        const unsigned p = coarse[i];
        const int l = (p >> 17) & 255;
        const int j = atomicAdd(&rc[l], 1);
        esrc[e0 + off[l] + j] = (int)(p & 0x1FFFFu);
    }
}

// ============================ edge attention ===============================
#define EA_ACC(kc, vc, EI) do {                                              \
    float sp = dot2h(u2h((kc).w), q3, dot2h(u2h((kc).z), q2,                 \
               dot2h(u2h((kc).y), q1, dot2h(u2h((kc).x), q0, 0.f))));        \
    sp += __shfl_xor(sp, 1);                                                 \
    float sc = __expf(fminf(fmaxf(sp * 0.25f, -5.f), 5.f));                  \
    sc = ((EI) < nb) ? sc : 0.f;                                             \
    a0 += sc * UB0((vc).x);                                                  \
    a1 += sc * UB1((vc).x);                                                  \
    a2 += sc * UB2((vc).x);                                                  \
    a3 += sc * UB3((vc).x);                                                  \
    a4 += sc * UB0((vc).y);                                                  \
    a5 += sc * UB1((vc).y);                                                  \
    a6 += sc * UB2((vc).y);                                                  \
    a7 += sc * UB3((vc).y);                                                  \
    z += sc;                                                                 \
} while (0)

__global__ __launch_bounds__(256) void edge_attn_k(
    const _Float16* __restrict__ Qh, const unsigned char* __restrict__ KV,
    const int* __restrict__ row_ptr, const int* __restrict__ esrc,
    unsigned short* __restrict__ attnb, int nodeOff, int nodeEnd)
{
    const int wave = threadIdx.x >> 6, lane = threadIdx.x & 63;
    const int node = nodeOff + blockIdx.x * 4 + wave;
    if (node >= nodeEnd) return;
    const int g = lane & 15, p = lane >> 4;
    const uint4 qv = *(const uint4*)&Qh[(size_t)node * 128 + g * 8];
    const h2f q0 = u2h(qv.x), q1 = u2h(qv.y), q2 = u2h(qv.z), q3 = u2h(qv.w);
    const int e0 = row_ptr[node], e1 = row_ptr[node + 1];
    const int cnt = e1 - e0;
    const int e1m1 = e1 - 1;
    float a0 = 0.f, a1 = 0.f, a2 = 0.f, a3 = 0.f;
    float a4 = 0.f, a5 = 0.f, a6 = 0.f, a7 = 0.f, z = 0.f;
    for (int base = 0; base < cnt; base += 64) {
        const int nb = min(cnt - base, 64);
        const int eb = e0 + base + p;
        {
            const int s0 = esrc[min(eb, e1m1)];
            const unsigned char* r = KV + (size_t)((unsigned)s0 * 384u);
            const int s1 = esrc[min(eb + 4, e1m1)];
            const unsigned char* rB = KV + (size_t)((unsigned)s1 * 384u);
            uint4 kvA = *(const uint4*)(r + g * 16);
            uint2 vvA = *(const uint2*)(r + 256 + g * 8);
            uint4 kvB = *(const uint4*)(rB + g * 16);
            uint2 vvB = *(const uint2*)(rB + 256 + g * 8);
            for (int j = 0; j < nb; j += 8) {
                {   // group A: edges j..j+3
                    const uint4 kc = kvA; const uint2 vc = vvA;
                    if (j + 8 < nb) {                    // wave-uniform
                        const int sn = esrc[min(eb + j + 8, e1m1)];
                        const unsigned char* rn = KV + (size_t)((unsigned)sn * 384u);
                        kvA = *(const uint4*)(rn + g * 16);
                        vvA = *(const uint2*)(rn + 256 + g * 8);
                    }
                    EA_ACC(kc, vc, j + p);
                }
                {   // group B: edges j+4..j+7 (masked if beyond nb)
                    const uint4 kc = kvB; const uint2 vc = vvB;
                    if (j + 12 < nb) {                   // wave-uniform
                        const int sn = esrc[min(eb + j + 12, e1m1)];
                        const unsigned char* rn = KV + (size_t)((unsigned)sn * 384u);
                        kvB = *(const uint4*)(rn + g * 16);
                        vvB = *(const uint2*)(rn + 256 + g * 8);
                    }
                    EA_ACC(kc, vc, j + 4 + p);
                }
            }
        }
    }
    a0 += __shfl_xor(a0, 16); a0 += __shfl_xor(a0, 32);
    a1 += __shfl_xor(a1, 16); a1 += __shfl_xor(a1, 32);
    a2 += __shfl_xor(a2, 16); a2 += __shfl_xor(a2, 32);
    a3 += __shfl_xor(a3, 16); a3 += __shfl_xor(a3, 32);
    a4 += __shfl_xor(a4, 16); a4 += __shfl_xor(a4, 32);
    a5 += __shfl_xor(a5, 16); a5 += __shfl_xor(a5, 32);
    a6 += __shfl_xor(a6, 16); a6 += __shfl_xor(a6, 32);
    a7 += __shfl_xor(a7, 16); a7 += __shfl_xor(a7, 32);
    z  += __shfl_xor(z, 16);  z  += __shfl_xor(z, 32);
    const float inv = 1.f / (z * VSCALE);
    const float c = 128.f * z;
    if (p == 0) {
        uint4 o;
        o.x = pk2((a0 - c) * inv, (a1 - c) * inv);
        o.y = pk2((a2 - c) * inv, (a3 - c) * inv);
        o.z = pk2((a4 - c) * inv, (a5 - c) * inv);
        o.w = pk2((a6 - c) * inv, (a7 - c) * inv);
        *(uint4*)&attnb[(size_t)node * 128 + g * 8] = o;
    }
}

// ============================ BN apply (folds finalize) ====================
__global__ __launch_bounds__(256) void bn_apply_b_k(const unsigned short* __restrict__ X,
                                                    const float* __restrict__ rstats,
                                                    const float* __restrict__ gma,
                                                    const float* __restrict__ bta,
                                                    float invN, int total8,
                                                    float* __restrict__ out)
{
    __shared__ float aff[256];
    if (threadIdx.x < 128) {
        const int c = threadIdx.x;
        const float mu = rstats[c] * invN;
        const float var = rstats[128 + c] * invN - mu * mu;
        const float isg = rsqrtf(var + EPS) * gma[c];
        aff[c] = isg;
        aff[128 + c] = bta[c] - mu * isg;
    }
    __syncthreads();
    for (int i = blockIdx.x * blockDim.x + threadIdx.x; i < total8;
         i += gridDim.x * blockDim.x) {
        const int c8 = (i & 15) * 8;
        const float4 sc0 = *(const float4*)&aff[c8];
        const float4 sc1 = *(const float4*)&aff[c8 + 4];
        const float4 sh0 = *(const float4*)&aff[128 + c8];
        const float4 sh1 = *(const float4*)&aff[128 + c8 + 4];
        const uint4 v = ((const uint4*)X)[i];
        float4 o0, o1;
        o0.x = b2f((unsigned short)(v.x & 0xffff)) * sc0.x + sh0.x;
        o0.y = b2f((unsigned short)(v.x >> 16))    * sc0.y + sh0.y;
        o0.z = b2f((unsigned short)(v.y & 0xffff)) * sc0.z + sh0.z;
        o0.w = b2f((unsigned short)(v.y >> 16))    * sc0.w + sh0.w;
        o1.x = b2f((unsigned short)(v.z & 0xffff)) * sc1.x + sh1.x;
        o1.y = b2f((unsigned short)(v.z >> 16))    * sc1.y + sh1.y;
        o1.z = b2f((unsigned short)(v.w & 0xffff)) * sc1.z + sh1.z;
        o1.w = b2f((unsigned short)(v.w >> 16))    * sc1.w + sh1.w;
        ((float4*)out)[i * 2]     = o0;
        ((float4*)out)[i * 2 + 1] = o1;
    }
}

// ============================ launch =======================================
extern "C" void kernel_launch(void* const* d_in, const int* in_sizes, int n_in,
                              void* d_out, int out_size, void* d_ws, size_t ws_size,
                              hipStream_t stream)
{
    const float* h   = (const float*)d_in[0];
    const float* Wq  = (const float*)d_in[1];
    const float* Wk  = (const float*)d_in[2];
    const float* Wv  = (const float*)d_in[3];
    const float* Wo  = (const float*)d_in[4];
    const float* bo  = (const float*)d_in[5];
    const float* g1  = (const float*)d_in[6];
    const float* b1  = (const float*)d_in[7];
    const float* Wf1 = (const float*)d_in[8];
    const float* bf1 = (const float*)d_in[9];
    const float* Wf2 = (const float*)d_in[10];
    const float* bf2 = (const float*)d_in[11];
    const float* g2  = (const float*)d_in[12];
    const float* b2  = (const float*)d_in[13];
    const int*   src = (const int*)d_in[14];
    const int*   dstv= (const int*)d_in[15];
    const int N = in_sizes[0] / 128;
    const int E = in_sizes[14];
    const int B = (N + 255) >> 8;
    const float invN = 1.f / (float)N;

    // ---- workspace layout ----
    unsigned short* Wt = (unsigned short*)d_ws;               // 131072 bf16
    float* stats1 = (float*)((char*)d_ws + 262144);           // 256
    float* stats2 = stats1 + 256;                             // 256
    int* bCnt = (int*)(stats2 + 256);                         // 512
    int* bOff = bCnt + 512;                                   // 513
    int* bCur = bOff + 513;                                   // 512
    uintptr_t big = ((uintptr_t)(bCur + 512) + 255) & ~(uintptr_t)255;
    _Float16* Qh = (_Float16*)big;                            // N*128 f16  (N*256B)
    unsigned char* KV = (unsigned char*)(Qh + (size_t)N * 128);   // N*384B packed K|V
    uintptr_t a2 = ((uintptr_t)(KV + (size_t)N * 384) + 255) & ~(uintptr_t)255;
    unsigned short* attnb = (unsigned short*)a2;              // N*128 bf16
    unsigned short* xb = attnb + (size_t)N * 128;             // N*128 bf16
    int* row_ptr = (int*)(xb + (size_t)N * 128);              // N+1
    // overlays (lifetimes disjoint):
    unsigned* coarse = (unsigned*)attnb;   // CSR temp; attnb born at edge_attn
    int* esrc = (int*)xb;                  // CSR out; xb born at Wo-GEMM
    unsigned short* hidden = (unsigned short*)Qh;  // N*256 bf16 (N*512B over Qh+KV head)
    unsigned short* yb = attnb;            // FFN2 bf16 out; attnb dead after Wo-GEMM
    // fold outputs: past hidden end, inside Qh+KV region (KV dead after edge_attn)
    uintptr_t fb = (big + (size_t)N * 512 + 255) & ~(uintptr_t)255;
    float* aff1 = (float*)fb;                          // 256 f
    float* b1f  = aff1 + 256;                          // 256 f
    unsigned short* W1f = (unsigned short*)(b1f + 256);// 256*128 bf16 (64KB)

    unsigned short* Wf1T = Wt + 65536;
    unsigned short* Wf2T = Wt + 98304;

    float* out = (float*)d_out;
    const dim3 b256(256);
    const dim3 b512(512);
    const int tiles64 = (N + 63) / 64;
    const int tiles32 = (N + 31) / 32;

    hipMemsetAsync(stats1, 0, 4096, stream);

    // ---- weight prep ----
    prep_all_k<<<dim3(512), b256, 0, stream>>>(Wq, Wk, Wv, Wo, Wf1, Wf2, Wt);

    // ---- CSR build ----
    bucket_cnt_k<<<dim3(256), b256, 0, stream>>>(dstv, E, bCnt);
    bucket_scan_k<<<dim3(1), dim3(512), 0, stream>>>(bCnt, B, bOff, bCur);
    coarse_k<<<dim3((E + CCH - 1) / CCH), dim3(512), 0, stream>>>(src, dstv, E, bCur, coarse);
    fine_k<<<dim3(B), b256, 0, stream>>>(coarse, bOff, B, N, row_ptr, esrc);

    // ---- fused QKV (single-pass over h; W in regs; packed epilogue) ----
    qkv3_k<<<dim3(1024), b512, 0, stream>>>(h, Wt, Qh, KV, N, tiles32);

    // ---- sparse attention -> attnb bf16 (single launch) ----
    edge_attn_k<<<dim3((N + 3) / 4), b256, 0, stream>>>(
        Qh, KV, row_ptr, esrc, attnb, 0, N);

    // ---- x = h + attn @ Wo + bo (bf16 out) ; BN1 raw moments ----
    gemm3_k<128, 128, 1, 1, 0><<<dim3(512, 1), b512, 0, stream>>>(
        attnb, Wt + 49152, bo, h, xb, N, 128, tiles64, nullptr, stats1);

    // ---- fold BN1 into FFN1 weights; emit aff1 for FFN2 resid ----
    fold_bn1_k<<<dim3(1), b256, 0, stream>>>(Wf1T, stats1, g1, b1, bf1, invN,
                                             W1f, b1f, aff1);

    // ---- FFN1: single-pass GEMM (all 256 cols) with folded weights, relu ----
    gemm3_k<128, 256, 0, 0, 1><<<dim3(512, 1), b512, 0, stream>>>(
        xb, W1f, b1f, nullptr, hidden, N, 256, tiles32, nullptr, nullptr);

    // ---- FFN2: resid = BN1(x) via aff1; BN2 raw moments -> yb bf16 ----
    gemm3_k<256, 128, 3, 1, 0><<<dim3(512, 1), b512, 0, stream>>>(
        hidden, Wf2T, bf2, xb, yb, N, 128, tiles32, aff1, stats2);

    // ---- BN2 apply (finalize folded): yb bf16 -> out fp32 ----
    bn_apply_b_k<<<dim3(1024), b256, 0, stream>>>(yb, stats2, g2, b2, invN, N * 16, out);
}